// Round 8
// baseline (241.796 us; speedup 1.0000x reference)
//
#include <hip/hip_runtime.h>
#include <hip/hip_bf16.h>

#define TT 4096
#define DD 1024
#define TBB 1024
#define WBB 256

typedef __attribute__((ext_vector_type(8))) _Float16 half8;
typedef __attribute__((ext_vector_type(4))) _Float16 half4;
typedef __attribute__((ext_vector_type(16))) float f32x16;

__device__ __forceinline__ unsigned short f2h(float v) {
  _Float16 h = (_Float16)v;
  return *reinterpret_cast<unsigned short*>(&h);
}
__device__ __forceinline__ float h2f(unsigned short u) {
  _Float16 h = *reinterpret_cast<_Float16*>(&u);
  return (float)h;
}

__device__ __forceinline__ void gl_lds16(const unsigned short* g, unsigned short* l) {
  __builtin_amdgcn_global_load_lds(
      (const __attribute__((address_space(1))) void*)(unsigned long long)(g),
      (__attribute__((address_space(3))) void*)(unsigned long long)(l),
      16, 0, 0);
}

__device__ __forceinline__ float waveSum(float v) {
#pragma unroll
  for (int o = 32; o > 0; o >>= 1) v += __shfl_down(v, o, 64);
  return v;
}
__device__ __forceinline__ float bSum(float v) {
#pragma unroll
  for (int o = 32; o > 0; o >>= 1) v += __shfl_xor(v, o, 64);
  return v;
}
__device__ __forceinline__ float bMax(float v) {
#pragma unroll
  for (int o = 32; o > 0; o >>= 1) v = fmaxf(v, __shfl_xor(v, o, 64));
  return v;
}

// 64x64-tile GEMM body (4 waves, BK=64, swizzled LDS). lA/lB are 2*2048-short
// scratch. EPI: 0 plain, 1 -> 1-acc, 2 -> 1-acc + symmetric mirror,
// 4 -> rank-8 ent/dep epilogue.
template <int EPI, typename OutT>
__device__ __forceinline__ void g64_body(
    const unsigned short* __restrict__ Ab, const unsigned short* __restrict__ Bb,
    OutT* __restrict__ Cb, int K, int lda, int ldb, int ldc,
    int bx, int by,
    const float* __restrict__ e0, const float* __restrict__ e1,
    const float* __restrict__ e2, const float* __restrict__ e3,
    unsigned short* __restrict__ lA, unsigned short* __restrict__ lB)
{
  const int m0 = by * 64, n0 = bx * 64;
  const int tid = threadIdx.x, wave = tid >> 6, lane = tid & 63;
  const int wm = (wave >> 1) * 32, wn = (wave & 1) * 32;
  const int srow = lane >> 2;
  const int grow = wave * 16 + srow;
  const int scol = (((lane & 3) ^ ((grow >> 1) & 3))) * 8;
  const int l31 = lane & 31, khi = lane >> 5;
  const int sw2 = (l31 >> 1) & 3;

  f32x16 acc = {};

  for (int k0 = 0; k0 < K; k0 += 64) {
#pragma unroll
    for (int h = 0; h < 2; ++h) {
      gl_lds16(Ab + (long)(m0 + grow) * lda + (k0 + h * 32 + scol), &lA[h * 2048 + wave * 512]);
      gl_lds16(Bb + (long)(n0 + grow) * ldb + (k0 + h * 32 + scol), &lB[h * 2048 + wave * 512]);
    }
    __syncthreads();

    half8 af[4], bfr[4];
#pragma unroll
    for (int ks = 0; ks < 4; ++ks) {
      af[ks] = *(const half8*)&lA[(ks >> 1) * 2048 + (wm + l31) * 32 + ((((ks & 1) * 2 + khi) ^ sw2) * 8)];
      bfr[ks] = *(const half8*)&lB[(ks >> 1) * 2048 + (wn + l31) * 32 + ((((ks & 1) * 2 + khi) ^ sw2) * 8)];
    }
#pragma unroll
    for (int ks = 0; ks < 4; ++ks)
      acc = __builtin_amdgcn_mfma_f32_32x32x16_f16(af[ks], bfr[ks], acc, 0, 0, 0);
    __syncthreads();
  }

  float Ef[4], Df[4];
  if constexpr (EPI == 4) {
    const int col0 = n0 + wn + l31;
#pragma unroll
    for (int j = 0; j < 4; ++j) {
      Ef[j] = e2[j * 1024 + col0];
      Df[j] = e3[j * 1024 + col0];
    }
  }
#pragma unroll
  for (int r = 0; r < 16; ++r) {
    const int row = m0 + wm + khi * 4 + (r & 3) + 8 * (r >> 2);
    const int col = n0 + wn + l31;
    float v = acc[r];
    if constexpr (EPI == 1 || EPI == 2) v = 1.0f - v;
    if constexpr (EPI == 4) {
      const float4 en = *(const float4*)(e0 + (long)row * 4);
      const float4 dp = *(const float4*)(e1 + (long)row * 4);
      v += en.x * Ef[0] + en.y * Ef[1] + en.z * Ef[2] + en.w * Ef[3]
         + dp.x * Df[0] + dp.y * Df[1] + dp.z * Df[2] + dp.w * Df[3];
    }
    const long ci = (long)row * ldc + col;
    if constexpr (sizeof(OutT) == 2) {
      Cb[ci] = (OutT)f2h(v);
    } else {
      Cb[ci] = v;
    }
  }

  if constexpr (EPI == 2) {
    // Off-diagonal tile: also write mirrored tile at (by<->bx), exact symmetry.
    if (bx != by) {
      unsigned short* mir = lA;            // 32*68 = 2176 shorts scratch
      const int lc = wn + l31;
#pragma unroll
      for (int chunk = 0; chunk < 2; ++chunk) {
        __syncthreads();
        if ((lc >> 5) == chunk) {
#pragma unroll
          for (int r = 0; r < 16; ++r) {
            const int lr = wm + khi * 4 + (r & 3) + 8 * (r >> 2);
            mir[(lc & 31) * 68 + lr] = f2h(1.0f - acc[r]);
          }
        }
        __syncthreads();
        const int cl = tid >> 3, co = (tid & 7) * 8;
        const ushort4 a = *(const ushort4*)&mir[cl * 68 + co];
        const ushort4 b = *(const ushort4*)&mir[cl * 68 + co + 4];
        unsigned short* dst = (unsigned short*)Cb + (long)(n0 + chunk * 32 + cl) * ldc + m0 + co;
        *(ushort4*)dst = a;
        *(ushort4*)(dst + 4) = b;
      }
    }
  }
}

// 128x128-tile GEMM body (4 waves, BK=64, swizzled LDS), fp16 out.
// lA/lB are 2*4096-short scratch.
__device__ __forceinline__ void g128_body(
    const unsigned short* __restrict__ Ab, const unsigned short* __restrict__ Bb,
    unsigned short* __restrict__ Cb, int K, int lda, int ldb, int ldc,
    int bx, int by,
    unsigned short* __restrict__ lA, unsigned short* __restrict__ lB)
{
  const int m0 = by * 128, n0 = bx * 128;
  const int tid = threadIdx.x, wave = tid >> 6, lane = tid & 63;
  const int wm = (wave >> 1) * 64, wn = (wave & 1) * 64;
  const int srow = lane >> 2;
  const int scol = (((lane & 3) ^ ((srow >> 1) & 3))) * 8;
  const int l31 = lane & 31, khi = lane >> 5;
  const int sw2 = (l31 >> 1) & 3;

  f32x16 acc[2][2] = {};

  for (int k0 = 0; k0 < K; k0 += 64) {
#pragma unroll
    for (int h = 0; h < 2; ++h)
#pragma unroll
      for (int t = 0; t < 2; ++t) {
        const int r = wave * 32 + t * 16 + srow;
        gl_lds16(Ab + (long)(m0 + r) * lda + (k0 + h * 32 + scol), &lA[h * 4096 + wave * 1024 + t * 512]);
        gl_lds16(Bb + (long)(n0 + r) * ldb + (k0 + h * 32 + scol), &lB[h * 4096 + wave * 1024 + t * 512]);
      }
    __syncthreads();

    half8 af[2][4], bfr[2][4];
#pragma unroll
    for (int mi = 0; mi < 2; ++mi)
#pragma unroll
      for (int ks = 0; ks < 4; ++ks)
        af[mi][ks] = *(const half8*)&lA[(ks >> 1) * 4096 + (wm + mi * 32 + l31) * 32 + ((((ks & 1) * 2 + khi) ^ sw2) * 8)];
#pragma unroll
    for (int ni = 0; ni < 2; ++ni)
#pragma unroll
      for (int ks = 0; ks < 4; ++ks)
        bfr[ni][ks] = *(const half8*)&lB[(ks >> 1) * 4096 + (wn + ni * 32 + l31) * 32 + ((((ks & 1) * 2 + khi) ^ sw2) * 8)];

#pragma unroll
    for (int ks = 0; ks < 4; ++ks)
#pragma unroll
      for (int mi = 0; mi < 2; ++mi)
#pragma unroll
        for (int ni = 0; ni < 2; ++ni)
          acc[mi][ni] = __builtin_amdgcn_mfma_f32_32x32x16_f16(af[mi][ks], bfr[ni][ks], acc[mi][ni], 0, 0, 0);
    __syncthreads();
  }

#pragma unroll
  for (int mi = 0; mi < 2; ++mi)
#pragma unroll
    for (int ni = 0; ni < 2; ++ni)
#pragma unroll
      for (int r = 0; r < 16; ++r) {
        const int row = m0 + wm + mi * 32 + khi * 4 + (r & 3) + 8 * (r >> 2);
        const int col = n0 + wn + ni * 32 + l31;
        Cb[(long)row * ldc + col] = f2h(acc[mi][ni][r]);
      }
}

// Standalone 64-tile GEMM wrapper (used for the final out GEMM).
template <int EPI, typename OutT>
__global__ __launch_bounds__(256) void gemm_s(
    const unsigned short* __restrict__ A, const unsigned short* __restrict__ B,
    OutT* __restrict__ C,
    int K, int lda, int ldb, int ldc,
    int zbase, int zdiv,
    long sAi, long sAj, long sBi, long sBj, long sCi, long sCj,
    long sAz, long sBz, long sCz,
    const float* __restrict__ e0, const float* __restrict__ e1,
    const float* __restrict__ e2, const float* __restrict__ e3)
{
  __shared__ __align__(16) unsigned short lA[2 * 2048];
  __shared__ __align__(16) unsigned short lB[2 * 2048];

  if constexpr (EPI == 2) {
    if (blockIdx.x < blockIdx.y) return;
  }
  const int z = blockIdx.z, gz = zbase + z;
  const int zi = gz / zdiv, zj = gz - zi * zdiv;
  const unsigned short* Ab = A + (long)zi * sAi + (long)zj * sAj + (long)z * sAz;
  const unsigned short* Bb = B + (long)zi * sBi + (long)zj * sBj + (long)z * sBz;
  OutT* Cb = C + (long)zi * sCi + (long)zj * sCj + (long)z * sCz;
  g64_body<EPI, OutT>(Ab, Bb, Cb, K, lda, ldb, ldc, blockIdx.x, blockIdx.y,
                      e0, e1, e2, e3, lA, lB);
}

// Mega GEMM launch #1 — all GEMMs that depend only on prep (one flat grid):
//  [0,512)      QK projection, 128-tile: z = b>>8, by = (b&255)>>3, bx = b&7
//  [512,1536)   Vt[d,t] = Wv[d,:]·x[t,:]   (V projection, direct-transposed)
//  [1536,2560)  div diag blocks 1-xu·xu^T  (EPI2 symmetric mirror)
//  [2560,2816)  WFh = WoB @ W2T^T fold     (K=256)
// Long (QK) blocks first -> short blocks form the drain tail.
__global__ __launch_bounds__(256) void mega1_kernel(
    const unsigned short* __restrict__ xh, const unsigned short* __restrict__ Wh,
    unsigned short* __restrict__ QKV,
    unsigned short* __restrict__ Vt,
    const unsigned short* __restrict__ xu, unsigned short* __restrict__ divb,
    const unsigned short* __restrict__ WoB, const unsigned short* __restrict__ W2T,
    unsigned short* __restrict__ WFh)
{
  __shared__ __align__(16) unsigned short lbuf[16384];  // 32 KB union

  int b = blockIdx.x;
  if (b < 512) {
    const int z = b >> 8, rem = b & 255, by = rem >> 3, bx = rem & 7;
    g128_body(xh, Wh + (long)z * DD * DD, QKV + (long)z * TT * DD,
              DD, DD, DD, DD, bx, by, lbuf, lbuf + 8192);
    return;
  }
  b -= 512;
  if (b < 1024) {
    const int bx = b & 63, by = b >> 6;
    g64_body<0, unsigned short>(Wh + (size_t)2 * DD * DD, xh, Vt, DD, DD, DD, TT, bx, by,
                                nullptr, nullptr, nullptr, nullptr, lbuf, lbuf + 4096);
    return;
  }
  b -= 1024;
  if (b < 1024) {
    const int z = b >> 8, r = b & 255, bx = r & 15, by = r >> 4;
    if (bx < by) return;  // lower triangle mirrored by upper
    const unsigned short* Xu = xu + (long)z * TBB * DD;
    g64_body<2, unsigned short>(Xu, Xu, divb + (long)z * TBB * TBB,
                                DD, DD, DD, TBB, bx, by,
                                nullptr, nullptr, nullptr, nullptr, lbuf, lbuf + 4096);
    return;
  }
  b -= 1024;
  {
    const int zj = b >> 6, r = b & 63, bx = r & 3, by = r >> 2;
    g64_body<0, unsigned short>(WoB + zj * 256, W2T, WFh + zj * 256,
                                256, DD, 256, DD, bx, by,
                                nullptr, nullptr, nullptr, nullptr, lbuf, lbuf + 4096);
  }
}

// sim GEMM: C(fp16) = A*B^T + APh, 128x128, LDS-staged, swizzled.
__global__ __launch_bounds__(256) void sim_gemm(
    const unsigned short* __restrict__ A, const unsigned short* __restrict__ B,
    unsigned short* __restrict__ C,
    const unsigned short* __restrict__ APh)
{
  __shared__ __align__(16) unsigned short lA[2][4096];
  __shared__ __align__(16) unsigned short lB[2][4096];

  const int gz = blockIdx.z;
  const int zi = gz >> 2, zj = gz & 3;
  const unsigned short* Ab = A + (long)zi * (TBB * DD) + zj * WBB;
  const unsigned short* Bb = B + (long)zi * (TBB * DD) + zj * WBB;
  unsigned short* Cb = C + (long)gz * TBB * TBB;

  const int m0 = blockIdx.y * 128, n0 = blockIdx.x * 128;
  const int tid = threadIdx.x, wave = tid >> 6, lane = tid & 63;
  const int wm = (wave >> 1) * 64, wn = (wave & 1) * 64;
  const int srow = lane >> 2;
  const int scol = ((lane & 3) ^ ((srow >> 1) & 3)) * 8;
  const int l31 = lane & 31, khi = lane >> 5;
  const int sw2 = (l31 >> 1) & 3;

  f32x16 acc[2][2] = {};

  for (int k0 = 0; k0 < WBB; k0 += 64) {
#pragma unroll
    for (int h = 0; h < 2; ++h)
#pragma unroll
      for (int t = 0; t < 2; ++t) {
        const int r = wave * 32 + t * 16 + srow;
        gl_lds16(Ab + (long)(m0 + r) * DD + (k0 + h * 32 + scol), &lA[h][wave * 1024 + t * 512]);
        gl_lds16(Bb + (long)(n0 + r) * DD + (k0 + h * 32 + scol), &lB[h][wave * 1024 + t * 512]);
      }
    __syncthreads();

    half8 af[2][4], bfr[2][4];
#pragma unroll
    for (int mi = 0; mi < 2; ++mi)
#pragma unroll
      for (int ks = 0; ks < 4; ++ks)
        af[mi][ks] = *(const half8*)&lA[ks >> 1][(wm + mi * 32 + l31) * 32 + ((((ks & 1) * 2 + khi) ^ sw2) * 8)];
#pragma unroll
    for (int ni = 0; ni < 2; ++ni)
#pragma unroll
      for (int ks = 0; ks < 4; ++ks)
        bfr[ni][ks] = *(const half8*)&lB[ks >> 1][(wn + ni * 32 + l31) * 32 + ((((ks & 1) * 2 + khi) ^ sw2) * 8)];

#pragma unroll
    for (int ks = 0; ks < 4; ++ks)
#pragma unroll
      for (int mi = 0; mi < 2; ++mi)
#pragma unroll
        for (int ni = 0; ni < 2; ++ni)
          acc[mi][ni] = __builtin_amdgcn_mfma_f32_32x32x16_f16(af[mi][ks], bfr[ni][ks], acc[mi][ni], 0, 0, 0);
    __syncthreads();
  }

#pragma unroll
  for (int mi = 0; mi < 2; ++mi)
#pragma unroll
    for (int ni = 0; ni < 2; ++ni)
#pragma unroll
      for (int r = 0; r < 16; ++r) {
        const int row = m0 + wm + mi * 32 + khi * 4 + (r & 3) + 8 * (r >> 2);
        const int col = n0 + wn + ni * 32 + l31;
        Cb[(long)row * TBB + col] = f2h(acc[mi][ni][r] + h2f(APh[(long)row * 1024 + col]));
      }
}

// ctx = (attw * (1+dep[k])) @ Vb, 64x128 tile (A-tile/exp2 shared by 2 n-tiles).
// attw recomputed from sim(fp16) + per-row B. Output in reassembled layout
// ctxR[t, zj*256+col]. y==16 side-blocks run entnorm (stats complete by launch).
__global__ __launch_bounds__(256) void ctx_gemm_s(
    const unsigned short* __restrict__ simh, const float* __restrict__ dep2,
    const float* __restrict__ Brow,
    const unsigned short* __restrict__ Vt, unsigned short* __restrict__ ctxR,
    float* __restrict__ ent2)
{
  const int tid = threadIdx.x;

  if (blockIdx.y == 16) {
    if (blockIdx.x != 0 || blockIdx.z >= 4) return;
    const int b = blockIdx.z;
    float4 v[4];
    float4 a = {0.f, 0.f, 0.f, 0.f};
#pragma unroll
    for (int p = 0; p < 4; ++p) {
      v[p] = *(const float4*)(ent2 + ((long)b * 1024 + tid + p * 256) * 4);
      a.x += fabsf(v[p].x); a.y += fabsf(v[p].y);
      a.z += fabsf(v[p].z); a.w += fabsf(v[p].w);
    }
    a.x = waveSum(a.x); a.y = waveSum(a.y);
    a.z = waveSum(a.z); a.w = waveSum(a.w);
    __shared__ float red[4][4];
    if ((tid & 63) == 0) {
      const int w = tid >> 6;
      red[w][0] = a.x; red[w][1] = a.y; red[w][2] = a.z; red[w][3] = a.w;
    }
    __syncthreads();
    float4 sc;
    sc.x = 1.f / fmaxf(red[0][0] + red[1][0] + red[2][0] + red[3][0], 1e-12f);
    sc.y = 1.f / fmaxf(red[0][1] + red[1][1] + red[2][1] + red[3][1], 1e-12f);
    sc.z = 1.f / fmaxf(red[0][2] + red[1][2] + red[2][2] + red[3][2], 1e-12f);
    sc.w = 1.f / fmaxf(red[0][3] + red[1][3] + red[2][3] + red[3][3], 1e-12f);
#pragma unroll
    for (int p = 0; p < 4; ++p) {
      float4 o = v[p];
      o.x *= sc.x; o.y *= sc.y; o.z *= sc.z; o.w *= sc.w;
      *(float4*)(ent2 + ((long)b * 1024 + tid + p * 256) * 4) = o;
    }
    return;
  }

  __shared__ __align__(16) unsigned short lA[2][2048];
  __shared__ __align__(16) unsigned short lB[2][4096];
  __shared__ __align__(16) unsigned short sDepH[1024];

  const int gz = blockIdx.z, zi = gz >> 2, zj = gz & 3;
  const int m0 = blockIdx.y * 64, n0 = blockIdx.x * 128;
  const int wave = tid >> 6, lane = tid & 63;
  const int wm = (wave >> 1) * 32, wn0 = (wave & 1) * 64;
  const int srow = lane >> 2;
  const int grow = wave * 16 + srow;
  const int scol = ((lane & 3) ^ ((grow >> 1) & 3)) * 8;
  const int l31 = lane & 31, khi = lane >> 5;
  const int sw2 = (l31 >> 1) & 3;

#pragma unroll
  for (int p = 0; p < 4; ++p)
    sDepH[tid + p * 256] =
        f2h(1.f + dep2[((long)zi * 1024 + tid + p * 256) * 4 + zj]);
  __syncthreads();

  const float B0 = Brow[(long)gz * 1024 + m0 + (tid >> 3)];
  const float B1 = Brow[(long)gz * 1024 + m0 + 32 + (tid >> 3)];

  const unsigned short* Ab = simh + (long)gz * TBB * TBB;
  const unsigned short* Bb = Vt + (long)(zj * 256) * TT + (long)zi * 1024;

  f32x16 acc[2] = {};

  for (int k0 = 0; k0 < 1024; k0 += 64) {
#pragma unroll
    for (int h = 0; h < 2; ++h) {
      gl_lds16(Bb + (long)(n0 + grow) * TT + (k0 + h * 32 + scol), &lB[h][wave * 512]);
      gl_lds16(Bb + (long)(n0 + 64 + grow) * TT + (k0 + h * 32 + scol), &lB[h][2048 + wave * 512]);
    }
#pragma unroll
    for (int h = 0; h < 2; ++h)
#pragma unroll
      for (int p = 0; p < 2; ++p) {
        const int idx = p * 1024 + tid * 4;
        const int row = idx >> 5, col = idx & 31;
        const ushort4 wv = *(const ushort4*)(Ab + (long)(m0 + row) * 1024 + k0 + h * 32 + col);
        const float Bp = p ? B1 : B0;
        half4 ev;
        ev.x = (_Float16)exp2f(fmaf(h2f(wv.x), 1.4426950408889634f, -Bp));
        ev.y = (_Float16)exp2f(fmaf(h2f(wv.y), 1.4426950408889634f, -Bp));
        ev.z = (_Float16)exp2f(fmaf(h2f(wv.z), 1.4426950408889634f, -Bp));
        ev.w = (_Float16)exp2f(fmaf(h2f(wv.w), 1.4426950408889634f, -Bp));
        const half4 dv = *(const half4*)&sDepH[k0 + h * 32 + col];
        half4 pv = ev * dv;
        const int pcol = (((col >> 3) ^ ((row >> 1) & 3)) << 3) | (col & 7);
        *(half4*)&lA[h][row * 32 + pcol] = pv;
      }
    __syncthreads();

    half8 af[4], bfr[2][4];
#pragma unroll
    for (int ks = 0; ks < 4; ++ks) {
      af[ks] = *(const half8*)&lA[ks >> 1][(wm + l31) * 32 + ((((ks & 1) * 2 + khi) ^ sw2) * 8)];
#pragma unroll
      for (int n = 0; n < 2; ++n)
        bfr[n][ks] = *(const half8*)&lB[ks >> 1][(wn0 + n * 32 + l31) * 32 + ((((ks & 1) * 2 + khi) ^ sw2) * 8)];
    }
#pragma unroll
    for (int ks = 0; ks < 4; ++ks)
#pragma unroll
      for (int n = 0; n < 2; ++n)
        acc[n] = __builtin_amdgcn_mfma_f32_32x32x16_f16(af[ks], bfr[n][ks], acc[n], 0, 0, 0);
    __syncthreads();
  }

#pragma unroll
  for (int n = 0; n < 2; ++n)
#pragma unroll
    for (int r = 0; r < 16; ++r) {
      const int row = m0 + wm + khi * 4 + (r & 3) + 8 * (r >> 2);
      const int col = n0 + wn0 + n * 32 + l31;
      ctxR[((long)zi * 1024 + row) * 1024 + zj * 256 + col] = f2h(acc[n][r]);
    }
}

// Mega preprocessing kernel — only WIDE-parallel parts (no serial tails).
__global__ __launch_bounds__(256) void prep_kernel(
    const float* __restrict__ x, const float* __restrict__ Wq,
    const float* __restrict__ Wk, const float* __restrict__ Wv,
    const float* __restrict__ Wo, const float* __restrict__ W2,
    unsigned short* __restrict__ xh, unsigned short* __restrict__ xu,
    unsigned short* __restrict__ Wh, unsigned short* __restrict__ APh,
    unsigned short* __restrict__ WoB, unsigned short* __restrict__ W2T,
    float* __restrict__ Efold, float* __restrict__ Dfold)
{
  __shared__ float red[4];
  int b = blockIdx.x;
  const int tid = threadIdx.x;

  if (b < 4096) {
    const int t = b;
    const float4 v = *((const float4*)(x + (long)t * DD) + tid);
    float ss = v.x * v.x + v.y * v.y + v.z * v.z + v.w * v.w;
    ss = waveSum(ss);
    if ((tid & 63) == 0) red[tid >> 6] = ss;
    __syncthreads();
    const float tot = red[0] + red[1] + red[2] + red[3];
    const float inv = 1.f / fmaxf(sqrtf(tot), 1e-12f);
    ushort4 h, u;
    h.x = f2h(v.x); h.y = f2h(v.y); h.z = f2h(v.z); h.w = f2h(v.w);
    u.x = f2h(v.x * inv); u.y = f2h(v.y * inv); u.z = f2h(v.z * inv); u.w = f2h(v.w * inv);
    *((ushort4*)(xh + (long)t * DD) + tid) = h;
    *((ushort4*)(xu + (long)t * DD) + tid) = u;
    return;
  }
  b -= 4096;
  if (b < 3072) {
    const long idx4 = ((long)b * 256 + tid) * 4;
    const int which = (int)(idx4 >> 20);
    const long loc = idx4 & ((1L << 20) - 1);
    const float* src = (which == 0) ? Wq : ((which == 1) ? Wk : Wv);
    const float4 v = *(const float4*)(src + loc);
    ushort4 h;
    h.x = f2h(v.x); h.y = f2h(v.y); h.z = f2h(v.z); h.w = f2h(v.w);
    *(ushort4*)(Wh + idx4) = h;
    return;
  }
  b -= 3072;
  if (b < 1024) {
    const int p = b;
#pragma unroll
    for (int t = 0; t < 2; ++t) {
      const int pr = tid + t * 256;
      const float e = (float)pr * (1.0f / 512.0f);
      const float ang = (float)p * exp2f(e * -13.287712379549449f);
      float s, c;
      sincosf(ang, &s, &c);
      ushort2 o;
      o.x = f2h(s); o.y = f2h(c);
      *(ushort2*)(APh + (long)p * 1024 + 2 * pr) = o;
    }
    return;
  }
  b -= 1024;
  if (b < 1024) {
    const long idx4 = ((long)b * 256 + tid) * 4;
    const float4 v = *(const float4*)(Wo + idx4);
    ushort4 h;
    h.x = f2h(v.x); h.y = f2h(v.y); h.z = f2h(v.z); h.w = f2h(v.w);
    *(ushort4*)(WoB + idx4) = h;
    return;
  }
  b -= 1024;
  if (b < 256) {
    const int w = b;
    W2T[tid * 256 + w] = f2h(W2[w * 258 + tid]);
    return;
  }
  b -= 256;
  {
    // Efold/Dfold: wave-parallel over K (lane=w), butterfly reduce.
    const int wave = tid >> 6, lane = tid & 63;
    float we[4], wd[4];
#pragma unroll
    for (int u = 0; u < 4; ++u) {
      we[u] = W2[(lane * 4 + u) * 258 + 256];
      wd[u] = W2[(lane * 4 + u) * 258 + 257];
    }
    for (int i = 0; i < 16; ++i) {
      const int pidx = (b * 4 + wave) * 16 + i;  // 0..4095
      const int j = pidx >> 10, d = pidx & 1023;
      const float4 v = *(const float4*)(Wo + (long)d * 1024 + j * 256 + lane * 4);
      float se = v.x * we[0] + v.y * we[1] + v.z * we[2] + v.w * we[3];
      float sd = v.x * wd[0] + v.y * wd[1] + v.z * wd[2] + v.w * wd[3];
      se = bSum(se);
      sd = bSum(sd);
      if (lane == 0) {
        Efold[j * 1024 + d] = se;
        Dfold[j * 1024 + d] = sd;
      }
    }
  }
}

// Wave-per-row stats, div row shared across the 4 j's of block-row bi.
__global__ __launch_bounds__(256) void stats_kernel(
    const unsigned short* __restrict__ sim, const unsigned short* __restrict__ divb,
    float* __restrict__ dep2, float* __restrict__ ent2,
    float* __restrict__ Brow)
{
  __shared__ __align__(16) unsigned short sDiv[1024];
  const int q = blockIdx.x, bi = blockIdx.y;
  const int tid = threadIdx.x;
  const int wave = tid >> 6, lane = tid & 63;

  *(ushort4*)&sDiv[tid * 4] =
      *(const ushort4*)(divb + ((long)bi * TBB + q) * TBB + tid * 4);
  __syncthreads();

  const int gz = bi * 4 + wave;
  const unsigned short* srow = sim + ((long)gz * TBB + q) * TBB;
  float s[16], d[16];
#pragma unroll
  for (int u = 0; u < 4; ++u) {
    const ushort4 sv = *(const ushort4*)(srow + u * 256 + lane * 4);
    const ushort4 dv = *(const ushort4*)&sDiv[u * 256 + lane * 4];
    s[u * 4 + 0] = h2f(sv.x); s[u * 4 + 1] = h2f(sv.y);
    s[u * 4 + 2] = h2f(sv.z); s[u * 4 + 3] = h2f(sv.w);
    d[u * 4 + 0] = h2f(dv.x); d[u * 4 + 1] = h2f(dv.y);
    d[u * 4 + 2] = h2f(dv.z); d[u * 4 + 3] = h2f(dv.w);
  }
  float m = s[0];
#pragma unroll
  for (int i = 1; i < 16; ++i) m = fmaxf(m, s[i]);
  m = bMax(m);
  const float mB = m * 1.4426950408889634f;
  float l = 0.f, ss = 0.f, dn = 0.f, ds = 0.f;
#pragma unroll
  for (int i = 0; i < 16; ++i) {
    const float e = exp2f(fmaf(s[i], 1.4426950408889634f, -mB));
    l += e; ss += e * s[i]; dn += e * d[i]; ds += d[i];
  }
  l = bSum(l); ss = bSum(ss); dn = bSum(dn); ds = bSum(ds);
  if (lane == 0) {
    const float Li = 1.f / l;
    const float lnL = logf(l);
    const long o2 = ((long)bi * 1024 + q) * 4 + wave;
    dep2[o2] = (dn * Li) / ds;
    ent2[o2] = (m + lnL - ss * Li) * 0.14426950408889634f;  // 1/ln(1024)
    Brow[(long)gz * TBB + q] = (m + lnL) * 1.4426950408889634f;
  }
}

extern "C" void kernel_launch(void* const* d_in, const int* in_sizes, int n_in,
                              void* d_out, int out_size, void* d_ws, size_t ws_size,
                              hipStream_t stream)
{
  const float* x  = (const float*)d_in[0];
  const float* Wq = (const float*)d_in[1];
  const float* Wk = (const float*)d_in[2];
  const float* Wv = (const float*)d_in[3];
  const float* Wo = (const float*)d_in[4];
  const float* W2 = (const float*)d_in[5];

  char* ws = (char*)d_ws;
  size_t off = 0;
  auto take = [&](size_t bytes) -> void* {
    void* p = ws + off;
    off += (bytes + 255) & ~(size_t)255;
    return p;
  };
  unsigned short* QKV = (unsigned short*)take((size_t)2 * TT * DD * 2);  // Q,K
  unsigned short* xh  = (unsigned short*)take((size_t)TT * DD * 2);
  unsigned short* xu  = (unsigned short*)take((size_t)TT * DD * 2);
  unsigned short* Wh  = (unsigned short*)take((size_t)3 * DD * DD * 2);
  unsigned short* WoB = (unsigned short*)take((size_t)DD * DD * 2);
  unsigned short* W2T = (unsigned short*)take((size_t)256 * 256 * 2);
  unsigned short* WFh = (unsigned short*)take((size_t)DD * DD * 2);
  float* Efold = (float*)take((size_t)4 * DD * 4);
  float* Dfold = (float*)take((size_t)4 * DD * 4);
  unsigned short* APh = (unsigned short*)take((size_t)TBB * TBB * 2);
  unsigned short* divb = (unsigned short*)take((size_t)4 * TBB * TBB * 2);
  unsigned short* Vt = (unsigned short*)take((size_t)DD * TT * 2);
  unsigned short* simh = (unsigned short*)take((size_t)16 * TBB * TBB * 2);
  float* dep2 = (float*)take((size_t)TT * 4 * 4);
  float* ent2 = (float*)take((size_t)TT * 4 * 4);
  float* Brow = (float*)take((size_t)16 * TBB * 4);
  unsigned short* ctxR = (unsigned short*)take((size_t)TT * DD * 2);
  (void)ws_size; (void)in_sizes; (void)n_in; (void)out_size;

  // 1) wide-parallel preprocessing
  prep_kernel<<<9536, 256, 0, stream>>>(x, Wq, Wk, Wv, Wo, W2,
                                        xh, xu, Wh, APh, WoB, W2T, Efold, Dfold);

  // 2) ALL prep-dependent GEMMs in one launch: QK (128-tile) + Vt + div + WFh
  mega1_kernel<<<2816, 256, 0, stream>>>(
      xh, Wh, QKV, Vt, xu, divb, WoB, W2T, WFh);

  const unsigned short* Qh = QKV;
  const unsigned short* Kh = QKV + (size_t)TT * DD;

  // 3) sim = Qb @ Kb^T + APh (fp16 out)
  sim_gemm<<<dim3(8, 8, 16), 256, 0, stream>>>(Qh, Kh, simh, APh);

  // 4) stats: block=(q,bi), wave=j; div row staged once in LDS
  stats_kernel<<<dim3(TBB, 4), 256, 0, stream>>>(simh, divb, dep2, ent2, Brow);

  // 5) ctxR = (exp2(s*log2e - B)*(1+dep[k])) @ Vb, 64x128 tile; + entnorm side-blocks
  ctx_gemm_s<<<dim3(2, 17, 16), 256, 0, stream>>>(simh, dep2, Brow, Vt, ctxR, ent2);

  // 6) out = ctxR @ WFh^T + rank-8 ent/dep epilogue
  gemm_s<4, float><<<dim3(16, 64, 1), 256, 0, stream>>>(
      ctxR, WFh, (float*)d_out,
      DD, DD, DD, DD, 0, 1,
      0, 0, 0, 0, 0, 0,
      0, 0, 0, ent2, dep2, Efold, Dfold);
}

// Round 9
// 225.182 us; speedup vs baseline: 1.0738x; 1.0738x over previous
//
#include <hip/hip_runtime.h>
#include <hip/hip_bf16.h>

#define TT 4096
#define DD 1024
#define TBB 1024
#define WBB 256

typedef __attribute__((ext_vector_type(8))) _Float16 half8;
typedef __attribute__((ext_vector_type(4))) _Float16 half4;
typedef __attribute__((ext_vector_type(16))) float f32x16;

__device__ __forceinline__ unsigned short f2h(float v) {
  _Float16 h = (_Float16)v;
  return *reinterpret_cast<unsigned short*>(&h);
}
__device__ __forceinline__ float h2f(unsigned short u) {
  _Float16 h = *reinterpret_cast<_Float16*>(&u);
  return (float)h;
}

__device__ __forceinline__ void gl_lds16(const unsigned short* g, unsigned short* l) {
  __builtin_amdgcn_global_load_lds(
      (const __attribute__((address_space(1))) void*)(unsigned long long)(g),
      (__attribute__((address_space(3))) void*)(unsigned long long)(l),
      16, 0, 0);
}

__device__ __forceinline__ float waveSum(float v) {
#pragma unroll
  for (int o = 32; o > 0; o >>= 1) v += __shfl_down(v, o, 64);
  return v;
}
__device__ __forceinline__ float bSum(float v) {
#pragma unroll
  for (int o = 32; o > 0; o >>= 1) v += __shfl_xor(v, o, 64);
  return v;
}
__device__ __forceinline__ float bMax(float v) {
#pragma unroll
  for (int o = 32; o > 0; o >>= 1) v = fmaxf(v, __shfl_xor(v, o, 64));
  return v;
}

// 64x64-tile GEMM body (4 waves, BK=64, swizzled LDS). Used by the final out
// GEMM only. EPI: 0 plain, 4 -> rank-8 ent/dep epilogue.
template <int EPI, typename OutT>
__device__ __forceinline__ void g64_body(
    const unsigned short* __restrict__ Ab, const unsigned short* __restrict__ Bb,
    OutT* __restrict__ Cb, int K, int lda, int ldb, int ldc,
    int bx, int by,
    const float* __restrict__ e0, const float* __restrict__ e1,
    const float* __restrict__ e2, const float* __restrict__ e3,
    unsigned short* __restrict__ lA, unsigned short* __restrict__ lB)
{
  const int m0 = by * 64, n0 = bx * 64;
  const int tid = threadIdx.x, wave = tid >> 6, lane = tid & 63;
  const int wm = (wave >> 1) * 32, wn = (wave & 1) * 32;
  const int srow = lane >> 2;
  const int grow = wave * 16 + srow;
  const int scol = (((lane & 3) ^ ((grow >> 1) & 3))) * 8;
  const int l31 = lane & 31, khi = lane >> 5;
  const int sw2 = (l31 >> 1) & 3;

  f32x16 acc = {};

  for (int k0 = 0; k0 < K; k0 += 64) {
#pragma unroll
    for (int h = 0; h < 2; ++h) {
      gl_lds16(Ab + (long)(m0 + grow) * lda + (k0 + h * 32 + scol), &lA[h * 2048 + wave * 512]);
      gl_lds16(Bb + (long)(n0 + grow) * ldb + (k0 + h * 32 + scol), &lB[h * 2048 + wave * 512]);
    }
    __syncthreads();

    half8 af[4], bfr[4];
#pragma unroll
    for (int ks = 0; ks < 4; ++ks) {
      af[ks] = *(const half8*)&lA[(ks >> 1) * 2048 + (wm + l31) * 32 + ((((ks & 1) * 2 + khi) ^ sw2) * 8)];
      bfr[ks] = *(const half8*)&lB[(ks >> 1) * 2048 + (wn + l31) * 32 + ((((ks & 1) * 2 + khi) ^ sw2) * 8)];
    }
#pragma unroll
    for (int ks = 0; ks < 4; ++ks)
      acc = __builtin_amdgcn_mfma_f32_32x32x16_f16(af[ks], bfr[ks], acc, 0, 0, 0);
    __syncthreads();
  }

  float Ef[4], Df[4];
  if constexpr (EPI == 4) {
    const int col0 = n0 + wn + l31;
#pragma unroll
    for (int j = 0; j < 4; ++j) {
      Ef[j] = e2[j * 1024 + col0];
      Df[j] = e3[j * 1024 + col0];
    }
  }
#pragma unroll
  for (int r = 0; r < 16; ++r) {
    const int row = m0 + wm + khi * 4 + (r & 3) + 8 * (r >> 2);
    const int col = n0 + wn + l31;
    float v = acc[r];
    if constexpr (EPI == 4) {
      const float4 en = *(const float4*)(e0 + (long)row * 4);
      const float4 dp = *(const float4*)(e1 + (long)row * 4);
      v += en.x * Ef[0] + en.y * Ef[1] + en.z * Ef[2] + en.w * Ef[3]
         + dp.x * Df[0] + dp.y * Df[1] + dp.z * Df[2] + dp.w * Df[3];
    }
    const long ci = (long)row * ldc + col;
    if constexpr (sizeof(OutT) == 2) {
      Cb[ci] = (OutT)f2h(v);
    } else {
      Cb[ci] = v;
    }
  }
}

// 128x128-tile GEMM body (4 waves, BK=64, swizzled LDS), fp16 out.
// lA/lB are 2*4096-short scratch. EPI: 0 plain, 1 -> 1.0f - v (div).
template <int EPI>
__device__ __forceinline__ void g128_body(
    const unsigned short* __restrict__ Ab, const unsigned short* __restrict__ Bb,
    unsigned short* __restrict__ Cb, int K, int lda, int ldb, int ldc,
    int bx, int by,
    unsigned short* __restrict__ lA, unsigned short* __restrict__ lB)
{
  const int m0 = by * 128, n0 = bx * 128;
  const int tid = threadIdx.x, wave = tid >> 6, lane = tid & 63;
  const int wm = (wave >> 1) * 64, wn = (wave & 1) * 64;
  const int srow = lane >> 2;
  const int scol = (((lane & 3) ^ ((srow >> 1) & 3))) * 8;
  const int l31 = lane & 31, khi = lane >> 5;
  const int sw2 = (l31 >> 1) & 3;

  f32x16 acc[2][2] = {};

  for (int k0 = 0; k0 < K; k0 += 64) {
#pragma unroll
    for (int h = 0; h < 2; ++h)
#pragma unroll
      for (int t = 0; t < 2; ++t) {
        const int r = wave * 32 + t * 16 + srow;
        gl_lds16(Ab + (long)(m0 + r) * lda + (k0 + h * 32 + scol), &lA[h * 4096 + wave * 1024 + t * 512]);
        gl_lds16(Bb + (long)(n0 + r) * ldb + (k0 + h * 32 + scol), &lB[h * 4096 + wave * 1024 + t * 512]);
      }
    __syncthreads();

    half8 af[2][4], bfr[2][4];
#pragma unroll
    for (int mi = 0; mi < 2; ++mi)
#pragma unroll
      for (int ks = 0; ks < 4; ++ks)
        af[mi][ks] = *(const half8*)&lA[(ks >> 1) * 4096 + (wm + mi * 32 + l31) * 32 + ((((ks & 1) * 2 + khi) ^ sw2) * 8)];
#pragma unroll
    for (int ni = 0; ni < 2; ++ni)
#pragma unroll
      for (int ks = 0; ks < 4; ++ks)
        bfr[ni][ks] = *(const half8*)&lB[(ks >> 1) * 4096 + (wn + ni * 32 + l31) * 32 + ((((ks & 1) * 2 + khi) ^ sw2) * 8)];

#pragma unroll
    for (int ks = 0; ks < 4; ++ks)
#pragma unroll
      for (int mi = 0; mi < 2; ++mi)
#pragma unroll
        for (int ni = 0; ni < 2; ++ni)
          acc[mi][ni] = __builtin_amdgcn_mfma_f32_32x32x16_f16(af[mi][ks], bfr[ni][ks], acc[mi][ni], 0, 0, 0);
    __syncthreads();
  }

#pragma unroll
  for (int mi = 0; mi < 2; ++mi)
#pragma unroll
    for (int ni = 0; ni < 2; ++ni)
#pragma unroll
      for (int r = 0; r < 16; ++r) {
        const int row = m0 + wm + mi * 32 + khi * 4 + (r & 3) + 8 * (r >> 2);
        const int col = n0 + wn + ni * 32 + l31;
        float v = acc[mi][ni][r];
        if constexpr (EPI == 1) v = 1.0f - v;
        Cb[(long)row * ldc + col] = f2h(v);
      }
}

// Standalone 64-tile GEMM wrapper (final out GEMM).
template <int EPI, typename OutT>
__global__ __launch_bounds__(256) void gemm_s(
    const unsigned short* __restrict__ A, const unsigned short* __restrict__ B,
    OutT* __restrict__ C,
    int K, int lda, int ldb, int ldc,
    const float* __restrict__ e0, const float* __restrict__ e1,
    const float* __restrict__ e2, const float* __restrict__ e3)
{
  __shared__ __align__(16) unsigned short lA[2 * 2048];
  __shared__ __align__(16) unsigned short lB[2 * 2048];
  g64_body<EPI, OutT>(A, B, C, K, lda, ldb, ldc, blockIdx.x, blockIdx.y,
                      e0, e1, e2, e3, lA, lB);
}

// Mega GEMM launch #1 — all GEMMs that depend only on prep, ALL 128-tile
// (uniform 32KB LDS, uniform block length, 66% MFMA ceiling):
//  [0,512)      QK projection: z=b>>8, by=(b&255)>>3, bx=b&7
//  [512,768)    Vt[d,t] = Wv[d,:]·x[t,:]: by=rem>>5 (8), bx=rem&31 (32)
//  [768,1024)   div full blocks 1-xu·xu^T: z=rem>>6, by=(rem&63)>>3, bx=rem&7
//  [1024,1088)  WFh = WoB @ W2T^T (K=256): zj=rem>>4, by=(rem&15)>>1, bx=rem&1
__global__ __launch_bounds__(256) void mega1_kernel(
    const unsigned short* __restrict__ xh, const unsigned short* __restrict__ Wh,
    unsigned short* __restrict__ QKV,
    unsigned short* __restrict__ Vt,
    const unsigned short* __restrict__ xu, unsigned short* __restrict__ divb,
    const unsigned short* __restrict__ WoB, const unsigned short* __restrict__ W2T,
    unsigned short* __restrict__ WFh)
{
  __shared__ __align__(16) unsigned short lbuf[16384];  // 32 KB

  int b = blockIdx.x;
  if (b < 512) {
    const int z = b >> 8, rem = b & 255, by = rem >> 3, bx = rem & 7;
    g128_body<0>(xh, Wh + (long)z * DD * DD, QKV + (long)z * TT * DD,
                 DD, DD, DD, DD, bx, by, lbuf, lbuf + 8192);
    return;
  }
  b -= 512;
  if (b < 256) {
    const int by = b >> 5, bx = b & 31;
    g128_body<0>(Wh + (size_t)2 * DD * DD, xh, Vt, DD, DD, DD, TT, bx, by,
                 lbuf, lbuf + 8192);
    return;
  }
  b -= 256;
  if (b < 256) {
    const int z = b >> 6, r = b & 63, by = r >> 3, bx = r & 7;
    const unsigned short* Xu = xu + (long)z * TBB * DD;
    g128_body<1>(Xu, Xu, divb + (long)z * TBB * TBB,
                 DD, DD, DD, TBB, bx, by, lbuf, lbuf + 8192);
    return;
  }
  b -= 256;
  {
    const int zj = b >> 4, r = b & 15, by = r >> 1, bx = r & 1;
    g128_body<0>(WoB + zj * 256, W2T, WFh + zj * 256,
                 256, DD, 256, DD, bx, by, lbuf, lbuf + 8192);
  }
}

// sim GEMM: C(fp16) = A*B^T + APh, 128x128, LDS-staged, swizzled.
__global__ __launch_bounds__(256) void sim_gemm(
    const unsigned short* __restrict__ A, const unsigned short* __restrict__ B,
    unsigned short* __restrict__ C,
    const unsigned short* __restrict__ APh)
{
  __shared__ __align__(16) unsigned short lA[2][4096];
  __shared__ __align__(16) unsigned short lB[2][4096];

  const int gz = blockIdx.z;
  const int zi = gz >> 2, zj = gz & 3;
  const unsigned short* Ab = A + (long)zi * (TBB * DD) + zj * WBB;
  const unsigned short* Bb = B + (long)zi * (TBB * DD) + zj * WBB;
  unsigned short* Cb = C + (long)gz * TBB * TBB;

  const int m0 = blockIdx.y * 128, n0 = blockIdx.x * 128;
  const int tid = threadIdx.x, wave = tid >> 6, lane = tid & 63;
  const int wm = (wave >> 1) * 64, wn = (wave & 1) * 64;
  const int srow = lane >> 2;
  const int scol = ((lane & 3) ^ ((srow >> 1) & 3)) * 8;
  const int l31 = lane & 31, khi = lane >> 5;
  const int sw2 = (l31 >> 1) & 3;

  f32x16 acc[2][2] = {};

  for (int k0 = 0; k0 < WBB; k0 += 64) {
#pragma unroll
    for (int h = 0; h < 2; ++h)
#pragma unroll
      for (int t = 0; t < 2; ++t) {
        const int r = wave * 32 + t * 16 + srow;
        gl_lds16(Ab + (long)(m0 + r) * DD + (k0 + h * 32 + scol), &lA[h][wave * 1024 + t * 512]);
        gl_lds16(Bb + (long)(n0 + r) * DD + (k0 + h * 32 + scol), &lB[h][wave * 1024 + t * 512]);
      }
    __syncthreads();

    half8 af[2][4], bfr[2][4];
#pragma unroll
    for (int mi = 0; mi < 2; ++mi)
#pragma unroll
      for (int ks = 0; ks < 4; ++ks)
        af[mi][ks] = *(const half8*)&lA[ks >> 1][(wm + mi * 32 + l31) * 32 + ((((ks & 1) * 2 + khi) ^ sw2) * 8)];
#pragma unroll
    for (int ni = 0; ni < 2; ++ni)
#pragma unroll
      for (int ks = 0; ks < 4; ++ks)
        bfr[ni][ks] = *(const half8*)&lB[ks >> 1][(wn + ni * 32 + l31) * 32 + ((((ks & 1) * 2 + khi) ^ sw2) * 8)];

#pragma unroll
    for (int ks = 0; ks < 4; ++ks)
#pragma unroll
      for (int mi = 0; mi < 2; ++mi)
#pragma unroll
        for (int ni = 0; ni < 2; ++ni)
          acc[mi][ni] = __builtin_amdgcn_mfma_f32_32x32x16_f16(af[mi][ks], bfr[ni][ks], acc[mi][ni], 0, 0, 0);
    __syncthreads();
  }

#pragma unroll
  for (int mi = 0; mi < 2; ++mi)
#pragma unroll
    for (int ni = 0; ni < 2; ++ni)
#pragma unroll
      for (int r = 0; r < 16; ++r) {
        const int row = m0 + wm + mi * 32 + khi * 4 + (r & 3) + 8 * (r >> 2);
        const int col = n0 + wn + ni * 32 + l31;
        Cb[(long)row * TBB + col] = f2h(acc[mi][ni][r] + h2f(APh[(long)row * 1024 + col]));
      }
}

// ctx = (attw * (1+dep[k])) @ Vb, 64x128 tile (A-tile/exp2 shared by 2 n-tiles).
// attw recomputed from sim(fp16) + per-row B. Output in reassembled layout
// ctxR[t, zj*256+col]. y==16 side-blocks run entnorm (stats complete by launch).
__global__ __launch_bounds__(256) void ctx_gemm_s(
    const unsigned short* __restrict__ simh, const float* __restrict__ dep2,
    const float* __restrict__ Brow,
    const unsigned short* __restrict__ Vt, unsigned short* __restrict__ ctxR,
    float* __restrict__ ent2)
{
  const int tid = threadIdx.x;

  if (blockIdx.y == 16) {
    if (blockIdx.x != 0 || blockIdx.z >= 4) return;
    const int b = blockIdx.z;
    float4 v[4];
    float4 a = {0.f, 0.f, 0.f, 0.f};
#pragma unroll
    for (int p = 0; p < 4; ++p) {
      v[p] = *(const float4*)(ent2 + ((long)b * 1024 + tid + p * 256) * 4);
      a.x += fabsf(v[p].x); a.y += fabsf(v[p].y);
      a.z += fabsf(v[p].z); a.w += fabsf(v[p].w);
    }
    a.x = waveSum(a.x); a.y = waveSum(a.y);
    a.z = waveSum(a.z); a.w = waveSum(a.w);
    __shared__ float red[4][4];
    if ((tid & 63) == 0) {
      const int w = tid >> 6;
      red[w][0] = a.x; red[w][1] = a.y; red[w][2] = a.z; red[w][3] = a.w;
    }
    __syncthreads();
    float4 sc;
    sc.x = 1.f / fmaxf(red[0][0] + red[1][0] + red[2][0] + red[3][0], 1e-12f);
    sc.y = 1.f / fmaxf(red[0][1] + red[1][1] + red[2][1] + red[3][1], 1e-12f);
    sc.z = 1.f / fmaxf(red[0][2] + red[1][2] + red[2][2] + red[3][2], 1e-12f);
    sc.w = 1.f / fmaxf(red[0][3] + red[1][3] + red[2][3] + red[3][3], 1e-12f);
#pragma unroll
    for (int p = 0; p < 4; ++p) {
      float4 o = v[p];
      o.x *= sc.x; o.y *= sc.y; o.z *= sc.z; o.w *= sc.w;
      *(float4*)(ent2 + ((long)b * 1024 + tid + p * 256) * 4) = o;
    }
    return;
  }

  __shared__ __align__(16) unsigned short lA[2][2048];
  __shared__ __align__(16) unsigned short lB[2][4096];
  __shared__ __align__(16) unsigned short sDepH[1024];

  const int gz = blockIdx.z, zi = gz >> 2, zj = gz & 3;
  const int m0 = blockIdx.y * 64, n0 = blockIdx.x * 128;
  const int wave = tid >> 6, lane = tid & 63;
  const int wm = (wave >> 1) * 32, wn0 = (wave & 1) * 64;
  const int srow = lane >> 2;
  const int grow = wave * 16 + srow;
  const int scol = ((lane & 3) ^ ((grow >> 1) & 3)) * 8;
  const int l31 = lane & 31, khi = lane >> 5;
  const int sw2 = (l31 >> 1) & 3;

#pragma unroll
  for (int p = 0; p < 4; ++p)
    sDepH[tid + p * 256] =
        f2h(1.f + dep2[((long)zi * 1024 + tid + p * 256) * 4 + zj]);
  __syncthreads();

  const float B0 = Brow[(long)gz * 1024 + m0 + (tid >> 3)];
  const float B1 = Brow[(long)gz * 1024 + m0 + 32 + (tid >> 3)];

  const unsigned short* Ab = simh + (long)gz * TBB * TBB;
  const unsigned short* Bb = Vt + (long)(zj * 256) * TT + (long)zi * 1024;

  f32x16 acc[2] = {};

  for (int k0 = 0; k0 < 1024; k0 += 64) {
#pragma unroll
    for (int h = 0; h < 2; ++h) {
      gl_lds16(Bb + (long)(n0 + grow) * TT + (k0 + h * 32 + scol), &lB[h][wave * 512]);
      gl_lds16(Bb + (long)(n0 + 64 + grow) * TT + (k0 + h * 32 + scol), &lB[h][2048 + wave * 512]);
    }
#pragma unroll
    for (int h = 0; h < 2; ++h)
#pragma unroll
      for (int p = 0; p < 2; ++p) {
        const int idx = p * 1024 + tid * 4;
        const int row = idx >> 5, col = idx & 31;
        const ushort4 wv = *(const ushort4*)(Ab + (long)(m0 + row) * 1024 + k0 + h * 32 + col);
        const float Bp = p ? B1 : B0;
        half4 ev;
        ev.x = (_Float16)exp2f(fmaf(h2f(wv.x), 1.4426950408889634f, -Bp));
        ev.y = (_Float16)exp2f(fmaf(h2f(wv.y), 1.4426950408889634f, -Bp));
        ev.z = (_Float16)exp2f(fmaf(h2f(wv.z), 1.4426950408889634f, -Bp));
        ev.w = (_Float16)exp2f(fmaf(h2f(wv.w), 1.4426950408889634f, -Bp));
        const half4 dv = *(const half4*)&sDepH[k0 + h * 32 + col];
        half4 pv = ev * dv;
        const int pcol = (((col >> 3) ^ ((row >> 1) & 3)) << 3) | (col & 7);
        *(half4*)&lA[h][row * 32 + pcol] = pv;
      }
    __syncthreads();

    half8 af[4], bfr[2][4];
#pragma unroll
    for (int ks = 0; ks < 4; ++ks) {
      af[ks] = *(const half8*)&lA[ks >> 1][(wm + l31) * 32 + ((((ks & 1) * 2 + khi) ^ sw2) * 8)];
#pragma unroll
      for (int n = 0; n < 2; ++n)
        bfr[n][ks] = *(const half8*)&lB[ks >> 1][(wn0 + n * 32 + l31) * 32 + ((((ks & 1) * 2 + khi) ^ sw2) * 8)];
    }
#pragma unroll
    for (int ks = 0; ks < 4; ++ks)
#pragma unroll
      for (int n = 0; n < 2; ++n)
        acc[n] = __builtin_amdgcn_mfma_f32_32x32x16_f16(af[ks], bfr[n][ks], acc[n], 0, 0, 0);
    __syncthreads();
  }

#pragma unroll
  for (int n = 0; n < 2; ++n)
#pragma unroll
    for (int r = 0; r < 16; ++r) {
      const int row = m0 + wm + khi * 4 + (r & 3) + 8 * (r >> 2);
      const int col = n0 + wn0 + n * 32 + l31;
      ctxR[((long)zi * 1024 + row) * 1024 + zj * 256 + col] = f2h(acc[n][r]);
    }
}

// Mega preprocessing kernel — only WIDE-parallel parts (no serial tails).
__global__ __launch_bounds__(256) void prep_kernel(
    const float* __restrict__ x, const float* __restrict__ Wq,
    const float* __restrict__ Wk, const float* __restrict__ Wv,
    const float* __restrict__ Wo, const float* __restrict__ W2,
    unsigned short* __restrict__ xh, unsigned short* __restrict__ xu,
    unsigned short* __restrict__ Wh, unsigned short* __restrict__ APh,
    unsigned short* __restrict__ WoB, unsigned short* __restrict__ W2T,
    float* __restrict__ Efold, float* __restrict__ Dfold)
{
  __shared__ float red[4];
  int b = blockIdx.x;
  const int tid = threadIdx.x;

  if (b < 4096) {
    const int t = b;
    const float4 v = *((const float4*)(x + (long)t * DD) + tid);
    float ss = v.x * v.x + v.y * v.y + v.z * v.z + v.w * v.w;
    ss = waveSum(ss);
    if ((tid & 63) == 0) red[tid >> 6] = ss;
    __syncthreads();
    const float tot = red[0] + red[1] + red[2] + red[3];
    const float inv = 1.f / fmaxf(sqrtf(tot), 1e-12f);
    ushort4 h, u;
    h.x = f2h(v.x); h.y = f2h(v.y); h.z = f2h(v.z); h.w = f2h(v.w);
    u.x = f2h(v.x * inv); u.y = f2h(v.y * inv); u.z = f2h(v.z * inv); u.w = f2h(v.w * inv);
    *((ushort4*)(xh + (long)t * DD) + tid) = h;
    *((ushort4*)(xu + (long)t * DD) + tid) = u;
    return;
  }
  b -= 4096;
  if (b < 3072) {
    const long idx4 = ((long)b * 256 + tid) * 4;
    const int which = (int)(idx4 >> 20);
    const long loc = idx4 & ((1L << 20) - 1);
    const float* src = (which == 0) ? Wq : ((which == 1) ? Wk : Wv);
    const float4 v = *(const float4*)(src + loc);
    ushort4 h;
    h.x = f2h(v.x); h.y = f2h(v.y); h.z = f2h(v.z); h.w = f2h(v.w);
    *(ushort4*)(Wh + idx4) = h;
    return;
  }
  b -= 3072;
  if (b < 1024) {
    const int p = b;
#pragma unroll
    for (int t = 0; t < 2; ++t) {
      const int pr = tid + t * 256;
      const float e = (float)pr * (1.0f / 512.0f);
      const float ang = (float)p * exp2f(e * -13.287712379549449f);
      float s, c;
      sincosf(ang, &s, &c);
      ushort2 o;
      o.x = f2h(s); o.y = f2h(c);
      *(ushort2*)(APh + (long)p * 1024 + 2 * pr) = o;
    }
    return;
  }
  b -= 1024;
  if (b < 1024) {
    const long idx4 = ((long)b * 256 + tid) * 4;
    const float4 v = *(const float4*)(Wo + idx4);
    ushort4 h;
    h.x = f2h(v.x); h.y = f2h(v.y); h.z = f2h(v.z); h.w = f2h(v.w);
    *(ushort4*)(WoB + idx4) = h;
    return;
  }
  b -= 1024;
  if (b < 256) {
    const int w = b;
    W2T[tid * 256 + w] = f2h(W2[w * 258 + tid]);
    return;
  }
  b -= 256;
  {
    // Efold/Dfold: wave-parallel over K (lane=w), butterfly reduce.
    const int wave = tid >> 6, lane = tid & 63;
    float we[4], wd[4];
#pragma unroll
    for (int u = 0; u < 4; ++u) {
      we[u] = W2[(lane * 4 + u) * 258 + 256];
      wd[u] = W2[(lane * 4 + u) * 258 + 257];
    }
    for (int i = 0; i < 16; ++i) {
      const int pidx = (b * 4 + wave) * 16 + i;  // 0..4095
      const int j = pidx >> 10, d = pidx & 1023;
      const float4 v = *(const float4*)(Wo + (long)d * 1024 + j * 256 + lane * 4);
      float se = v.x * we[0] + v.y * we[1] + v.z * we[2] + v.w * we[3];
      float sd = v.x * wd[0] + v.y * wd[1] + v.z * wd[2] + v.w * wd[3];
      se = bSum(se);
      sd = bSum(sd);
      if (lane == 0) {
        Efold[j * 1024 + d] = se;
        Dfold[j * 1024 + d] = sd;
      }
    }
  }
}

// Wave-per-row stats, div row shared across the 4 j's of block-row bi.
__global__ __launch_bounds__(256) void stats_kernel(
    const unsigned short* __restrict__ sim, const unsigned short* __restrict__ divb,
    float* __restrict__ dep2, float* __restrict__ ent2,
    float* __restrict__ Brow)
{
  __shared__ __align__(16) unsigned short sDiv[1024];
  const int q = blockIdx.x, bi = blockIdx.y;
  const int tid = threadIdx.x;
  const int wave = tid >> 6, lane = tid & 63;

  *(ushort4*)&sDiv[tid * 4] =
      *(const ushort4*)(divb + ((long)bi * TBB + q) * TBB + tid * 4);
  __syncthreads();

  const int gz = bi * 4 + wave;
  const unsigned short* srow = sim + ((long)gz * TBB + q) * TBB;
  float s[16], d[16];
#pragma unroll
  for (int u = 0; u < 4; ++u) {
    const ushort4 sv = *(const ushort4*)(srow + u * 256 + lane * 4);
    const ushort4 dv = *(const ushort4*)&sDiv[u * 256 + lane * 4];
    s[u * 4 + 0] = h2f(sv.x); s[u * 4 + 1] = h2f(sv.y);
    s[u * 4 + 2] = h2f(sv.z); s[u * 4 + 3] = h2f(sv.w);
    d[u * 4 + 0] = h2f(dv.x); d[u * 4 + 1] = h2f(dv.y);
    d[u * 4 + 2] = h2f(dv.z); d[u * 4 + 3] = h2f(dv.w);
  }
  float m = s[0];
#pragma unroll
  for (int i = 1; i < 16; ++i) m = fmaxf(m, s[i]);
  m = bMax(m);
  const float mB = m * 1.4426950408889634f;
  float l = 0.f, ss = 0.f, dn = 0.f, ds = 0.f;
#pragma unroll
  for (int i = 0; i < 16; ++i) {
    const float e = exp2f(fmaf(s[i], 1.4426950408889634f, -mB));
    l += e; ss += e * s[i]; dn += e * d[i]; ds += d[i];
  }
  l = bSum(l); ss = bSum(ss); dn = bSum(dn); ds = bSum(ds);
  if (lane == 0) {
    const float Li = 1.f / l;
    const float lnL = logf(l);
    const long o2 = ((long)bi * 1024 + q) * 4 + wave;
    dep2[o2] = (dn * Li) / ds;
    ent2[o2] = (m + lnL - ss * Li) * 0.14426950408889634f;  // 1/ln(1024)
    Brow[(long)gz * TBB + q] = (m + lnL) * 1.4426950408889634f;
  }
}

extern "C" void kernel_launch(void* const* d_in, const int* in_sizes, int n_in,
                              void* d_out, int out_size, void* d_ws, size_t ws_size,
                              hipStream_t stream)
{
  const float* x  = (const float*)d_in[0];
  const float* Wq = (const float*)d_in[1];
  const float* Wk = (const float*)d_in[2];
  const float* Wv = (const float*)d_in[3];
  const float* Wo = (const float*)d_in[4];
  const float* W2 = (const float*)d_in[5];

  char* ws = (char*)d_ws;
  size_t off = 0;
  auto take = [&](size_t bytes) -> void* {
    void* p = ws + off;
    off += (bytes + 255) & ~(size_t)255;
    return p;
  };
  unsigned short* QKV = (unsigned short*)take((size_t)2 * TT * DD * 2);  // Q,K
  unsigned short* xh  = (unsigned short*)take((size_t)TT * DD * 2);
  unsigned short* xu  = (unsigned short*)take((size_t)TT * DD * 2);
  unsigned short* Wh  = (unsigned short*)take((size_t)3 * DD * DD * 2);
  unsigned short* WoB = (unsigned short*)take((size_t)DD * DD * 2);
  unsigned short* W2T = (unsigned short*)take((size_t)256 * 256 * 2);
  unsigned short* WFh = (unsigned short*)take((size_t)DD * DD * 2);
  float* Efold = (float*)take((size_t)4 * DD * 4);
  float* Dfold = (float*)take((size_t)4 * DD * 4);
  unsigned short* APh = (unsigned short*)take((size_t)TBB * TBB * 2);
  unsigned short* divb = (unsigned short*)take((size_t)4 * TBB * TBB * 2);
  unsigned short* Vt = (unsigned short*)take((size_t)DD * TT * 2);
  unsigned short* simh = (unsigned short*)take((size_t)16 * TBB * TBB * 2);
  float* dep2 = (float*)take((size_t)TT * 4 * 4);
  float* ent2 = (float*)take((size_t)TT * 4 * 4);
  float* Brow = (float*)take((size_t)16 * TBB * 4);
  unsigned short* ctxR = (unsigned short*)take((size_t)TT * DD * 2);
  (void)ws_size; (void)in_sizes; (void)n_in; (void)out_size;

  // 1) wide-parallel preprocessing
  prep_kernel<<<9536, 256, 0, stream>>>(x, Wq, Wk, Wv, Wo, W2,
                                        xh, xu, Wh, APh, WoB, W2T, Efold, Dfold);

  // 2) ALL prep-dependent GEMMs, all 128-tile: QK + Vt + div(full) + WFh
  mega1_kernel<<<1088, 256, 0, stream>>>(
      xh, Wh, QKV, Vt, xu, divb, WoB, W2T, WFh);

  const unsigned short* Qh = QKV;
  const unsigned short* Kh = QKV + (size_t)TT * DD;

  // 3) sim = Qb @ Kb^T + APh (fp16 out)
  sim_gemm<<<dim3(8, 8, 16), 256, 0, stream>>>(Qh, Kh, simh, APh);

  // 4) stats: block=(q,bi), wave=j; div row staged once in LDS
  stats_kernel<<<dim3(TBB, 4), 256, 0, stream>>>(simh, divb, dep2, ent2, Brow);

  // 5) ctxR = (exp2(s*log2e - B)*(1+dep[k])) @ Vb, 64x128 tile; + entnorm side-blocks
  ctx_gemm_s<<<dim3(2, 17, 16), 256, 0, stream>>>(simh, dep2, Brow, Vt, ctxR, ent2);

  // 6) out = ctxR @ WFh^T + rank-8 ent/dep epilogue
  gemm_s<4, float><<<dim3(16, 64, 1), 256, 0, stream>>>(
      ctxR, WFh, (float*)d_out,
      DD, DD, DD, DD,
      ent2, dep2, Efold, Dfold);
}

// Round 10
// 224.629 us; speedup vs baseline: 1.0764x; 1.0025x over previous
//
#include <hip/hip_runtime.h>
#include <hip/hip_bf16.h>

#define TT 4096
#define DD 1024
#define TBB 1024
#define WBB 256

typedef __attribute__((ext_vector_type(8))) _Float16 half8;
typedef __attribute__((ext_vector_type(4))) _Float16 half4;
typedef __attribute__((ext_vector_type(16))) float f32x16;

__device__ __forceinline__ unsigned short f2h(float v) {
  _Float16 h = (_Float16)v;
  return *reinterpret_cast<unsigned short*>(&h);
}
__device__ __forceinline__ float h2f(unsigned short u) {
  _Float16 h = *reinterpret_cast<_Float16*>(&u);
  return (float)h;
}

__device__ __forceinline__ void gl_lds16(const unsigned short* g, unsigned short* l) {
  __builtin_amdgcn_global_load_lds(
      (const __attribute__((address_space(1))) void*)(unsigned long long)(g),
      (__attribute__((address_space(3))) void*)(unsigned long long)(l),
      16, 0, 0);
}

__device__ __forceinline__ float waveSum(float v) {
#pragma unroll
  for (int o = 32; o > 0; o >>= 1) v += __shfl_down(v, o, 64);
  return v;
}
__device__ __forceinline__ float bSum(float v) {
#pragma unroll
  for (int o = 32; o > 0; o >>= 1) v += __shfl_xor(v, o, 64);
  return v;
}
__device__ __forceinline__ float bMax(float v) {
#pragma unroll
  for (int o = 32; o > 0; o >>= 1) v = fmaxf(v, __shfl_xor(v, o, 64));
  return v;
}

// 64x64-tile GEMM body (4 waves, BK=64, swizzled LDS). Used by the final out
// GEMM only. EPI: 0 plain, 4 -> rank-8 ent/dep epilogue.
template <int EPI, typename OutT>
__device__ __forceinline__ void g64_body(
    const unsigned short* __restrict__ Ab, const unsigned short* __restrict__ Bb,
    OutT* __restrict__ Cb, int K, int lda, int ldb, int ldc,
    int bx, int by,
    const float* __restrict__ e0, const float* __restrict__ e1,
    const float* __restrict__ e2, const float* __restrict__ e3,
    unsigned short* __restrict__ lA, unsigned short* __restrict__ lB)
{
  const int m0 = by * 64, n0 = bx * 64;
  const int tid = threadIdx.x, wave = tid >> 6, lane = tid & 63;
  const int wm = (wave >> 1) * 32, wn = (wave & 1) * 32;
  const int srow = lane >> 2;
  const int grow = wave * 16 + srow;
  const int scol = (((lane & 3) ^ ((grow >> 1) & 3))) * 8;
  const int l31 = lane & 31, khi = lane >> 5;
  const int sw2 = (l31 >> 1) & 3;

  f32x16 acc = {};

  for (int k0 = 0; k0 < K; k0 += 64) {
#pragma unroll
    for (int h = 0; h < 2; ++h) {
      gl_lds16(Ab + (long)(m0 + grow) * lda + (k0 + h * 32 + scol), &lA[h * 2048 + wave * 512]);
      gl_lds16(Bb + (long)(n0 + grow) * ldb + (k0 + h * 32 + scol), &lB[h * 2048 + wave * 512]);
    }
    __syncthreads();

    half8 af[4], bfr[4];
#pragma unroll
    for (int ks = 0; ks < 4; ++ks) {
      af[ks] = *(const half8*)&lA[(ks >> 1) * 2048 + (wm + l31) * 32 + ((((ks & 1) * 2 + khi) ^ sw2) * 8)];
      bfr[ks] = *(const half8*)&lB[(ks >> 1) * 2048 + (wn + l31) * 32 + ((((ks & 1) * 2 + khi) ^ sw2) * 8)];
    }
#pragma unroll
    for (int ks = 0; ks < 4; ++ks)
      acc = __builtin_amdgcn_mfma_f32_32x32x16_f16(af[ks], bfr[ks], acc, 0, 0, 0);
    __syncthreads();
  }

  float Ef[4], Df[4];
  if constexpr (EPI == 4) {
    const int col0 = n0 + wn + l31;
#pragma unroll
    for (int j = 0; j < 4; ++j) {
      Ef[j] = e2[j * 1024 + col0];
      Df[j] = e3[j * 1024 + col0];
    }
  }
#pragma unroll
  for (int r = 0; r < 16; ++r) {
    const int row = m0 + wm + khi * 4 + (r & 3) + 8 * (r >> 2);
    const int col = n0 + wn + l31;
    float v = acc[r];
    if constexpr (EPI == 4) {
      const float4 en = *(const float4*)(e0 + (long)row * 4);
      const float4 dp = *(const float4*)(e1 + (long)row * 4);
      v += en.x * Ef[0] + en.y * Ef[1] + en.z * Ef[2] + en.w * Ef[3]
         + dp.x * Df[0] + dp.y * Df[1] + dp.z * Df[2] + dp.w * Df[3];
    }
    const long ci = (long)row * ldc + col;
    if constexpr (sizeof(OutT) == 2) {
      Cb[ci] = (OutT)f2h(v);
    } else {
      Cb[ci] = v;
    }
  }
}

// 128x128-tile GEMM body (4 waves, BK=64, swizzled LDS), fp16 out.
// lA/lB are 2*4096-short scratch. EPI: 0 plain, 1 -> 1.0f - v (div).
template <int EPI>
__device__ __forceinline__ void g128_body(
    const unsigned short* __restrict__ Ab, const unsigned short* __restrict__ Bb,
    unsigned short* __restrict__ Cb, int K, int lda, int ldb, int ldc,
    int bx, int by,
    unsigned short* __restrict__ lA, unsigned short* __restrict__ lB)
{
  const int m0 = by * 128, n0 = bx * 128;
  const int tid = threadIdx.x, wave = tid >> 6, lane = tid & 63;
  const int wm = (wave >> 1) * 64, wn = (wave & 1) * 64;
  const int srow = lane >> 2;
  const int scol = (((lane & 3) ^ ((srow >> 1) & 3))) * 8;
  const int l31 = lane & 31, khi = lane >> 5;
  const int sw2 = (l31 >> 1) & 3;

  f32x16 acc[2][2] = {};

  for (int k0 = 0; k0 < K; k0 += 64) {
#pragma unroll
    for (int h = 0; h < 2; ++h)
#pragma unroll
      for (int t = 0; t < 2; ++t) {
        const int r = wave * 32 + t * 16 + srow;
        gl_lds16(Ab + (long)(m0 + r) * lda + (k0 + h * 32 + scol), &lA[h * 4096 + wave * 1024 + t * 512]);
        gl_lds16(Bb + (long)(n0 + r) * ldb + (k0 + h * 32 + scol), &lB[h * 4096 + wave * 1024 + t * 512]);
      }
    __syncthreads();

    half8 af[2][4], bfr[2][4];
#pragma unroll
    for (int mi = 0; mi < 2; ++mi)
#pragma unroll
      for (int ks = 0; ks < 4; ++ks)
        af[mi][ks] = *(const half8*)&lA[(ks >> 1) * 4096 + (wm + mi * 32 + l31) * 32 + ((((ks & 1) * 2 + khi) ^ sw2) * 8)];
#pragma unroll
    for (int ni = 0; ni < 2; ++ni)
#pragma unroll
      for (int ks = 0; ks < 4; ++ks)
        bfr[ni][ks] = *(const half8*)&lB[(ks >> 1) * 4096 + (wn + ni * 32 + l31) * 32 + ((((ks & 1) * 2 + khi) ^ sw2) * 8)];

#pragma unroll
    for (int ks = 0; ks < 4; ++ks)
#pragma unroll
      for (int mi = 0; mi < 2; ++mi)
#pragma unroll
        for (int ni = 0; ni < 2; ++ni)
          acc[mi][ni] = __builtin_amdgcn_mfma_f32_32x32x16_f16(af[mi][ks], bfr[ni][ks], acc[mi][ni], 0, 0, 0);
    __syncthreads();
  }

#pragma unroll
  for (int mi = 0; mi < 2; ++mi)
#pragma unroll
    for (int ni = 0; ni < 2; ++ni)
#pragma unroll
      for (int r = 0; r < 16; ++r) {
        const int row = m0 + wm + mi * 32 + khi * 4 + (r & 3) + 8 * (r >> 2);
        const int col = n0 + wn + ni * 32 + l31;
        float v = acc[mi][ni][r];
        if constexpr (EPI == 1) v = 1.0f - v;
        Cb[(long)row * ldc + col] = f2h(v);
      }
}

// Mega GEMM launch #1 — all GEMMs that depend only on prep, ALL 128-tile.
// XCD-bijective swizzle (1088 = 8*136): each XCD gets a contiguous 136-block
// chunk -> B-panels L2-resident, A-panels reused 8x from L2.
//  [0,512)      QK projection: z=b>>8, by=(b&255)>>3, bx=b&7
//  [512,768)    Vt[d,t] = Wv[d,:]·x[t,:]: by=rem>>5 (8), bx=rem&31 (32)
//  [768,1024)   div full blocks 1-xu·xu^T: z=rem>>6, by=(rem&63)>>3, bx=rem&7
//  [1024,1088)  WFh = WoB @ W2T^T (K=256): zj=rem>>4, by=(rem&15)>>1, bx=rem&1
__global__ __launch_bounds__(256) void mega1_kernel(
    const unsigned short* __restrict__ xh, const unsigned short* __restrict__ Wh,
    unsigned short* __restrict__ QKV,
    unsigned short* __restrict__ Vt,
    const unsigned short* __restrict__ xu, unsigned short* __restrict__ divb,
    const unsigned short* __restrict__ WoB, const unsigned short* __restrict__ W2T,
    unsigned short* __restrict__ WFh)
{
  __shared__ __align__(16) unsigned short lbuf[16384];  // 32 KB

  int b = blockIdx.x;
  b = (b & 7) * 136 + (b >> 3);  // XCD-bijective chunking (1088 % 8 == 0)
  if (b < 512) {
    const int z = b >> 8, rem = b & 255, by = rem >> 3, bx = rem & 7;
    g128_body<0>(xh, Wh + (long)z * DD * DD, QKV + (long)z * TT * DD,
                 DD, DD, DD, DD, bx, by, lbuf, lbuf + 8192);
    return;
  }
  b -= 512;
  if (b < 256) {
    const int by = b >> 5, bx = b & 31;
    g128_body<0>(Wh + (size_t)2 * DD * DD, xh, Vt, DD, DD, DD, TT, bx, by,
                 lbuf, lbuf + 8192);
    return;
  }
  b -= 256;
  if (b < 256) {
    const int z = b >> 6, r = b & 63, by = r >> 3, bx = r & 7;
    const unsigned short* Xu = xu + (long)z * TBB * DD;
    g128_body<1>(Xu, Xu, divb + (long)z * TBB * TBB,
                 DD, DD, DD, TBB, bx, by, lbuf, lbuf + 8192);
    return;
  }
  b -= 256;
  {
    const int zj = b >> 4, r = b & 15, by = r >> 1, bx = r & 1;
    g128_body<0>(WoB + zj * 256, W2T, WFh + zj * 256,
                 256, DD, 256, DD, bx, by, lbuf, lbuf + 8192);
  }
}

// sim GEMM: C(fp16) = A*B^T + APh, 128x128, flat 1024-grid with XCD swizzle
// (each XCD owns whole gz's -> Q/K slices + APh L2-resident).
__global__ __launch_bounds__(256) void sim_gemm(
    const unsigned short* __restrict__ A, const unsigned short* __restrict__ B,
    unsigned short* __restrict__ C,
    const unsigned short* __restrict__ APh)
{
  __shared__ __align__(16) unsigned short lA[2][4096];
  __shared__ __align__(16) unsigned short lB[2][4096];

  int b = blockIdx.x;
  b = (b & 7) * 128 + (b >> 3);  // 1024 % 8 == 0, bijective
  const int gz = b >> 6, rem = b & 63;
  const int m0 = (rem >> 3) * 128, n0 = (rem & 7) * 128;

  const int zi = gz >> 2, zj = gz & 3;
  const unsigned short* Ab = A + (long)zi * (TBB * DD) + zj * WBB;
  const unsigned short* Bb = B + (long)zi * (TBB * DD) + zj * WBB;
  unsigned short* Cb = C + (long)gz * TBB * TBB;

  const int tid = threadIdx.x, wave = tid >> 6, lane = tid & 63;
  const int wm = (wave >> 1) * 64, wn = (wave & 1) * 64;
  const int srow = lane >> 2;
  const int scol = ((lane & 3) ^ ((srow >> 1) & 3)) * 8;
  const int l31 = lane & 31, khi = lane >> 5;
  const int sw2 = (l31 >> 1) & 3;

  f32x16 acc[2][2] = {};

  for (int k0 = 0; k0 < WBB; k0 += 64) {
#pragma unroll
    for (int h = 0; h < 2; ++h)
#pragma unroll
      for (int t = 0; t < 2; ++t) {
        const int r = wave * 32 + t * 16 + srow;
        gl_lds16(Ab + (long)(m0 + r) * DD + (k0 + h * 32 + scol), &lA[h][wave * 1024 + t * 512]);
        gl_lds16(Bb + (long)(n0 + r) * DD + (k0 + h * 32 + scol), &lB[h][wave * 1024 + t * 512]);
      }
    __syncthreads();

    half8 af[2][4], bfr[2][4];
#pragma unroll
    for (int mi = 0; mi < 2; ++mi)
#pragma unroll
      for (int ks = 0; ks < 4; ++ks)
        af[mi][ks] = *(const half8*)&lA[ks >> 1][(wm + mi * 32 + l31) * 32 + ((((ks & 1) * 2 + khi) ^ sw2) * 8)];
#pragma unroll
    for (int ni = 0; ni < 2; ++ni)
#pragma unroll
      for (int ks = 0; ks < 4; ++ks)
        bfr[ni][ks] = *(const half8*)&lB[ks >> 1][(wn + ni * 32 + l31) * 32 + ((((ks & 1) * 2 + khi) ^ sw2) * 8)];

#pragma unroll
    for (int ks = 0; ks < 4; ++ks)
#pragma unroll
      for (int mi = 0; mi < 2; ++mi)
#pragma unroll
        for (int ni = 0; ni < 2; ++ni)
          acc[mi][ni] = __builtin_amdgcn_mfma_f32_32x32x16_f16(af[mi][ks], bfr[ni][ks], acc[mi][ni], 0, 0, 0);
    __syncthreads();
  }

#pragma unroll
  for (int mi = 0; mi < 2; ++mi)
#pragma unroll
    for (int ni = 0; ni < 2; ++ni)
#pragma unroll
      for (int r = 0; r < 16; ++r) {
        const int row = m0 + wm + mi * 32 + khi * 4 + (r & 3) + 8 * (r >> 2);
        const int col = n0 + wn + ni * 32 + l31;
        Cb[(long)row * TBB + col] = f2h(acc[mi][ni][r] + h2f(APh[(long)row * 1024 + col]));
      }
}

// ctx = (attw * (1+dep[k])) @ Vb, 64x128 tile, flat 516-grid:
// b<4 -> entnorm; else XCD-swizzled work blocks (each XCD owns 2 gz ->
// sim slice + Vt slice L2-resident for the K=1024 re-reads).
__global__ __launch_bounds__(256) void ctx_gemm_s(
    const unsigned short* __restrict__ simh, const float* __restrict__ dep2,
    const float* __restrict__ Brow,
    const unsigned short* __restrict__ Vt, unsigned short* __restrict__ ctxR,
    float* __restrict__ ent2)
{
  const int tid = threadIdx.x;
  int b = blockIdx.x;

  if (b < 4) {
    // entnorm: L1-normalize ent2 over q for i-block b.
    float4 v[4];
    float4 a = {0.f, 0.f, 0.f, 0.f};
#pragma unroll
    for (int p = 0; p < 4; ++p) {
      v[p] = *(const float4*)(ent2 + ((long)b * 1024 + tid + p * 256) * 4);
      a.x += fabsf(v[p].x); a.y += fabsf(v[p].y);
      a.z += fabsf(v[p].z); a.w += fabsf(v[p].w);
    }
    a.x = waveSum(a.x); a.y = waveSum(a.y);
    a.z = waveSum(a.z); a.w = waveSum(a.w);
    __shared__ float red[4][4];
    if ((tid & 63) == 0) {
      const int w = tid >> 6;
      red[w][0] = a.x; red[w][1] = a.y; red[w][2] = a.z; red[w][3] = a.w;
    }
    __syncthreads();
    float4 sc;
    sc.x = 1.f / fmaxf(red[0][0] + red[1][0] + red[2][0] + red[3][0], 1e-12f);
    sc.y = 1.f / fmaxf(red[0][1] + red[1][1] + red[2][1] + red[3][1], 1e-12f);
    sc.z = 1.f / fmaxf(red[0][2] + red[1][2] + red[2][2] + red[3][2], 1e-12f);
    sc.w = 1.f / fmaxf(red[0][3] + red[1][3] + red[2][3] + red[3][3], 1e-12f);
#pragma unroll
    for (int p = 0; p < 4; ++p) {
      float4 o = v[p];
      o.x *= sc.x; o.y *= sc.y; o.z *= sc.z; o.w *= sc.w;
      *(float4*)(ent2 + ((long)b * 1024 + tid + p * 256) * 4) = o;
    }
    return;
  }
  b -= 4;
  b = (b & 7) * 64 + (b >> 3);  // 512 % 8 == 0, bijective
  const int gz = b >> 5, rem = b & 31;
  const int m0 = (rem >> 1) * 64, n0 = (rem & 1) * 128;
  const int zi = gz >> 2, zj = gz & 3;

  __shared__ __align__(16) unsigned short lA[2][2048];
  __shared__ __align__(16) unsigned short lB[2][4096];
  __shared__ __align__(16) unsigned short sDepH[1024];

  const int wave = tid >> 6, lane = tid & 63;
  const int wm = (wave >> 1) * 32, wn0 = (wave & 1) * 64;
  const int srow = lane >> 2;
  const int grow = wave * 16 + srow;
  const int scol = ((lane & 3) ^ ((grow >> 1) & 3)) * 8;
  const int l31 = lane & 31, khi = lane >> 5;
  const int sw2 = (l31 >> 1) & 3;

#pragma unroll
  for (int p = 0; p < 4; ++p)
    sDepH[tid + p * 256] =
        f2h(1.f + dep2[((long)zi * 1024 + tid + p * 256) * 4 + zj]);
  __syncthreads();

  const float B0 = Brow[(long)gz * 1024 + m0 + (tid >> 3)];
  const float B1 = Brow[(long)gz * 1024 + m0 + 32 + (tid >> 3)];

  const unsigned short* Ab = simh + (long)gz * TBB * TBB;
  const unsigned short* Bb = Vt + (long)(zj * 256) * TT + (long)zi * 1024;

  f32x16 acc[2] = {};

  for (int k0 = 0; k0 < 1024; k0 += 64) {
#pragma unroll
    for (int h = 0; h < 2; ++h) {
      gl_lds16(Bb + (long)(n0 + grow) * TT + (k0 + h * 32 + scol), &lB[h][wave * 512]);
      gl_lds16(Bb + (long)(n0 + 64 + grow) * TT + (k0 + h * 32 + scol), &lB[h][2048 + wave * 512]);
    }
#pragma unroll
    for (int h = 0; h < 2; ++h)
#pragma unroll
      for (int p = 0; p < 2; ++p) {
        const int idx = p * 1024 + tid * 4;
        const int row = idx >> 5, col = idx & 31;
        const ushort4 wv = *(const ushort4*)(Ab + (long)(m0 + row) * 1024 + k0 + h * 32 + col);
        const float Bp = p ? B1 : B0;
        half4 ev;
        ev.x = (_Float16)exp2f(fmaf(h2f(wv.x), 1.4426950408889634f, -Bp));
        ev.y = (_Float16)exp2f(fmaf(h2f(wv.y), 1.4426950408889634f, -Bp));
        ev.z = (_Float16)exp2f(fmaf(h2f(wv.z), 1.4426950408889634f, -Bp));
        ev.w = (_Float16)exp2f(fmaf(h2f(wv.w), 1.4426950408889634f, -Bp));
        const half4 dv = *(const half4*)&sDepH[k0 + h * 32 + col];
        half4 pv = ev * dv;
        const int pcol = (((col >> 3) ^ ((row >> 1) & 3)) << 3) | (col & 7);
        *(half4*)&lA[h][row * 32 + pcol] = pv;
      }
    __syncthreads();

    half8 af[4], bfr[2][4];
#pragma unroll
    for (int ks = 0; ks < 4; ++ks) {
      af[ks] = *(const half8*)&lA[ks >> 1][(wm + l31) * 32 + ((((ks & 1) * 2 + khi) ^ sw2) * 8)];
#pragma unroll
      for (int n = 0; n < 2; ++n)
        bfr[n][ks] = *(const half8*)&lB[ks >> 1][(wn0 + n * 32 + l31) * 32 + ((((ks & 1) * 2 + khi) ^ sw2) * 8)];
    }
#pragma unroll
    for (int ks = 0; ks < 4; ++ks)
#pragma unroll
      for (int n = 0; n < 2; ++n)
        acc[n] = __builtin_amdgcn_mfma_f32_32x32x16_f16(af[ks], bfr[n][ks], acc[n], 0, 0, 0);
    __syncthreads();
  }

#pragma unroll
  for (int n = 0; n < 2; ++n)
#pragma unroll
    for (int r = 0; r < 16; ++r) {
      const int row = m0 + wm + khi * 4 + (r & 3) + 8 * (r >> 2);
      const int col = n0 + wn0 + n * 32 + l31;
      ctxR[((long)zi * 1024 + row) * 1024 + zj * 256 + col] = f2h(acc[n][r]);
    }
}

// Final out GEMM: 64-tile, flat 1024-grid with XCD swizzle (WFh L2-resident).
__global__ __launch_bounds__(256) void out_kernel(
    const unsigned short* __restrict__ A, const unsigned short* __restrict__ B,
    float* __restrict__ C,
    const float* __restrict__ e0, const float* __restrict__ e1,
    const float* __restrict__ e2, const float* __restrict__ e3)
{
  __shared__ __align__(16) unsigned short lA[2 * 2048];
  __shared__ __align__(16) unsigned short lB[2 * 2048];
  int b = blockIdx.x;
  b = (b & 7) * 128 + (b >> 3);  // 1024 % 8 == 0, bijective
  g64_body<4, float>(A, B, C, DD, DD, DD, DD, b & 15, b >> 4,
                     e0, e1, e2, e3, lA, lB);
}

// Mega preprocessing kernel — only WIDE-parallel parts (no serial tails).
__global__ __launch_bounds__(256) void prep_kernel(
    const float* __restrict__ x, const float* __restrict__ Wq,
    const float* __restrict__ Wk, const float* __restrict__ Wv,
    const float* __restrict__ Wo, const float* __restrict__ W2,
    unsigned short* __restrict__ xh, unsigned short* __restrict__ xu,
    unsigned short* __restrict__ Wh, unsigned short* __restrict__ APh,
    unsigned short* __restrict__ WoB, unsigned short* __restrict__ W2T,
    float* __restrict__ Efold, float* __restrict__ Dfold)
{
  __shared__ float red[4];
  int b = blockIdx.x;
  const int tid = threadIdx.x;

  if (b < 4096) {
    const int t = b;
    const float4 v = *((const float4*)(x + (long)t * DD) + tid);
    float ss = v.x * v.x + v.y * v.y + v.z * v.z + v.w * v.w;
    ss = waveSum(ss);
    if ((tid & 63) == 0) red[tid >> 6] = ss;
    __syncthreads();
    const float tot = red[0] + red[1] + red[2] + red[3];
    const float inv = 1.f / fmaxf(sqrtf(tot), 1e-12f);
    ushort4 h, u;
    h.x = f2h(v.x); h.y = f2h(v.y); h.z = f2h(v.z); h.w = f2h(v.w);
    u.x = f2h(v.x * inv); u.y = f2h(v.y * inv); u.z = f2h(v.z * inv); u.w = f2h(v.w * inv);
    *((ushort4*)(xh + (long)t * DD) + tid) = h;
    *((ushort4*)(xu + (long)t * DD) + tid) = u;
    return;
  }
  b -= 4096;
  if (b < 3072) {
    const long idx4 = ((long)b * 256 + tid) * 4;
    const int which = (int)(idx4 >> 20);
    const long loc = idx4 & ((1L << 20) - 1);
    const float* src = (which == 0) ? Wq : ((which == 1) ? Wk : Wv);
    const float4 v = *(const float4*)(src + loc);
    ushort4 h;
    h.x = f2h(v.x); h.y = f2h(v.y); h.z = f2h(v.z); h.w = f2h(v.w);
    *(ushort4*)(Wh + idx4) = h;
    return;
  }
  b -= 3072;
  if (b < 1024) {
    const int p = b;
#pragma unroll
    for (int t = 0; t < 2; ++t) {
      const int pr = tid + t * 256;
      const float e = (float)pr * (1.0f / 512.0f);
      const float ang = (float)p * exp2f(e * -13.287712379549449f);
      float s, c;
      sincosf(ang, &s, &c);
      ushort2 o;
      o.x = f2h(s); o.y = f2h(c);
      *(ushort2*)(APh + (long)p * 1024 + 2 * pr) = o;
    }
    return;
  }
  b -= 1024;
  if (b < 1024) {
    const long idx4 = ((long)b * 256 + tid) * 4;
    const float4 v = *(const float4*)(Wo + idx4);
    ushort4 h;
    h.x = f2h(v.x); h.y = f2h(v.y); h.z = f2h(v.z); h.w = f2h(v.w);
    *(ushort4*)(WoB + idx4) = h;
    return;
  }
  b -= 1024;
  if (b < 256) {
    const int w = b;
    W2T[tid * 256 + w] = f2h(W2[w * 258 + tid]);
    return;
  }
  b -= 256;
  {
    // Efold/Dfold: wave-parallel over K (lane=w), butterfly reduce.
    const int wave = tid >> 6, lane = tid & 63;
    float we[4], wd[4];
#pragma unroll
    for (int u = 0; u < 4; ++u) {
      we[u] = W2[(lane * 4 + u) * 258 + 256];
      wd[u] = W2[(lane * 4 + u) * 258 + 257];
    }
    for (int i = 0; i < 16; ++i) {
      const int pidx = (b * 4 + wave) * 16 + i;  // 0..4095
      const int j = pidx >> 10, d = pidx & 1023;
      const float4 v = *(const float4*)(Wo + (long)d * 1024 + j * 256 + lane * 4);
      float se = v.x * we[0] + v.y * we[1] + v.z * we[2] + v.w * we[3];
      float sd = v.x * wd[0] + v.y * wd[1] + v.z * wd[2] + v.w * wd[3];
      se = bSum(se);
      sd = bSum(sd);
      if (lane == 0) {
        Efold[j * 1024 + d] = se;
        Dfold[j * 1024 + d] = sd;
      }
    }
  }
}

// Wave-per-row stats, div row shared across the 4 j's of block-row bi.
__global__ __launch_bounds__(256) void stats_kernel(
    const unsigned short* __restrict__ sim, const unsigned short* __restrict__ divb,
    float* __restrict__ dep2, float* __restrict__ ent2,
    float* __restrict__ Brow)
{
  __shared__ __align__(16) unsigned short sDiv[1024];
  const int q = blockIdx.x, bi = blockIdx.y;
  const int tid = threadIdx.x;
  const int wave = tid >> 6, lane = tid & 63;

  *(ushort4*)&sDiv[tid * 4] =
      *(const ushort4*)(divb + ((long)bi * TBB + q) * TBB + tid * 4);
  __syncthreads();

  const int gz = bi * 4 + wave;
  const unsigned short* srow = sim + ((long)gz * TBB + q) * TBB;
  float s[16], d[16];
#pragma unroll
  for (int u = 0; u < 4; ++u) {
    const ushort4 sv = *(const ushort4*)(srow + u * 256 + lane * 4);
    const ushort4 dv = *(const ushort4*)&sDiv[u * 256 + lane * 4];
    s[u * 4 + 0] = h2f(sv.x); s[u * 4 + 1] = h2f(sv.y);
    s[u * 4 + 2] = h2f(sv.z); s[u * 4 + 3] = h2f(sv.w);
    d[u * 4 + 0] = h2f(dv.x); d[u * 4 + 1] = h2f(dv.y);
    d[u * 4 + 2] = h2f(dv.z); d[u * 4 + 3] = h2f(dv.w);
  }
  float m = s[0];
#pragma unroll
  for (int i = 1; i < 16; ++i) m = fmaxf(m, s[i]);
  m = bMax(m);
  const float mB = m * 1.4426950408889634f;
  float l = 0.f, ss = 0.f, dn = 0.f, ds = 0.f;
#pragma unroll
  for (int i = 0; i < 16; ++i) {
    const float e = exp2f(fmaf(s[i], 1.4426950408889634f, -mB));
    l += e; ss += e * s[i]; dn += e * d[i]; ds += d[i];
  }
  l = bSum(l); ss = bSum(ss); dn = bSum(dn); ds = bSum(ds);
  if (lane == 0) {
    const float Li = 1.f / l;
    const float lnL = logf(l);
    const long o2 = ((long)bi * 1024 + q) * 4 + wave;
    dep2[o2] = (dn * Li) / ds;
    ent2[o2] = (m + lnL - ss * Li) * 0.14426950408889634f;  // 1/ln(1024)
    Brow[(long)gz * TBB + q] = (m + lnL) * 1.4426950408889634f;
  }
}

extern "C" void kernel_launch(void* const* d_in, const int* in_sizes, int n_in,
                              void* d_out, int out_size, void* d_ws, size_t ws_size,
                              hipStream_t stream)
{
  const float* x  = (const float*)d_in[0];
  const float* Wq = (const float*)d_in[1];
  const float* Wk = (const float*)d_in[2];
  const float* Wv = (const float*)d_in[3];
  const float* Wo = (const float*)d_in[4];
  const float* W2 = (const float*)d_in[5];

  char* ws = (char*)d_ws;
  size_t off = 0;
  auto take = [&](size_t bytes) -> void* {
    void* p = ws + off;
    off += (bytes + 255) & ~(size_t)255;
    return p;
  };
  unsigned short* QKV = (unsigned short*)take((size_t)2 * TT * DD * 2);  // Q,K
  unsigned short* xh  = (unsigned short*)take((size_t)TT * DD * 2);
  unsigned short* xu  = (unsigned short*)take((size_t)TT * DD * 2);
  unsigned short* Wh  = (unsigned short*)take((size_t)3 * DD * DD * 2);
  unsigned short* WoB = (unsigned short*)take((size_t)DD * DD * 2);
  unsigned short* W2T = (unsigned short*)take((size_t)256 * 256 * 2);
  unsigned short* WFh = (unsigned short*)take((size_t)DD * DD * 2);
  float* Efold = (float*)take((size_t)4 * DD * 4);
  float* Dfold = (float*)take((size_t)4 * DD * 4);
  unsigned short* APh = (unsigned short*)take((size_t)TBB * TBB * 2);
  unsigned short* divb = (unsigned short*)take((size_t)4 * TBB * TBB * 2);
  unsigned short* Vt = (unsigned short*)take((size_t)DD * TT * 2);
  unsigned short* simh = (unsigned short*)take((size_t)16 * TBB * TBB * 2);
  float* dep2 = (float*)take((size_t)TT * 4 * 4);
  float* ent2 = (float*)take((size_t)TT * 4 * 4);
  float* Brow = (float*)take((size_t)16 * TBB * 4);
  unsigned short* ctxR = (unsigned short*)take((size_t)TT * DD * 2);
  (void)ws_size; (void)in_sizes; (void)n_in; (void)out_size;

  // 1) wide-parallel preprocessing
  prep_kernel<<<9536, 256, 0, stream>>>(x, Wq, Wk, Wv, Wo, W2,
                                        xh, xu, Wh, APh, WoB, W2T, Efold, Dfold);

  // 2) ALL prep-dependent GEMMs, all 128-tile, XCD-chunked
  mega1_kernel<<<1088, 256, 0, stream>>>(
      xh, Wh, QKV, Vt, xu, divb, WoB, W2T, WFh);

  const unsigned short* Qh = QKV;
  const unsigned short* Kh = QKV + (size_t)TT * DD;

  // 3) sim = Qb @ Kb^T + APh (fp16 out), flat grid + XCD swizzle
  sim_gemm<<<1024, 256, 0, stream>>>(Qh, Kh, simh, APh);

  // 4) stats: block=(q,bi), wave=j; div row staged once in LDS
  stats_kernel<<<dim3(TBB, 4), 256, 0, stream>>>(simh, divb, dep2, ent2, Brow);

  // 5) ctxR + entnorm side-blocks, flat grid + XCD swizzle
  ctx_gemm_s<<<516, 256, 0, stream>>>(simh, dep2, Brow, Vt, ctxR, ent2);

  // 6) out = ctxR @ WFh^T + rank-8 ent/dep epilogue, flat grid + XCD swizzle
  out_kernel<<<1024, 256, 0, stream>>>(
      ctxR, WFh, (float*)d_out, ent2, dep2, Efold, Dfold);
}

// Round 11
// 218.881 us; speedup vs baseline: 1.1047x; 1.0263x over previous
//
#include <hip/hip_runtime.h>
#include <hip/hip_bf16.h>

#define TT 4096
#define DD 1024
#define TBB 1024
#define WBB 256

typedef __attribute__((ext_vector_type(8))) _Float16 half8;
typedef __attribute__((ext_vector_type(4))) _Float16 half4;
typedef __attribute__((ext_vector_type(16))) float f32x16;

__device__ __forceinline__ unsigned short f2h(float v) {
  _Float16 h = (_Float16)v;
  return *reinterpret_cast<unsigned short*>(&h);
}
__device__ __forceinline__ float h2f(unsigned short u) {
  _Float16 h = *reinterpret_cast<_Float16*>(&u);
  return (float)h;
}

__device__ __forceinline__ void gl_lds16(const unsigned short* g, unsigned short* l) {
  __builtin_amdgcn_global_load_lds(
      (const __attribute__((address_space(1))) void*)(unsigned long long)(g),
      (__attribute__((address_space(3))) void*)(unsigned long long)(l),
      16, 0, 0);
}

__device__ __forceinline__ float waveSum(float v) {
#pragma unroll
  for (int o = 32; o > 0; o >>= 1) v += __shfl_down(v, o, 64);
  return v;
}
__device__ __forceinline__ float bSum(float v) {
#pragma unroll
  for (int o = 32; o > 0; o >>= 1) v += __shfl_xor(v, o, 64);
  return v;
}
__device__ __forceinline__ float bMax(float v) {
#pragma unroll
  for (int o = 32; o > 0; o >>= 1) v = fmaxf(v, __shfl_xor(v, o, 64));
  return v;
}

// 64x64-tile GEMM body (4 waves, BK=64, swizzled LDS). Used by the final out
// GEMM only. EPI: 0 plain, 4 -> rank-8 ent/dep epilogue.
template <int EPI, typename OutT>
__device__ __forceinline__ void g64_body(
    const unsigned short* __restrict__ Ab, const unsigned short* __restrict__ Bb,
    OutT* __restrict__ Cb, int K, int lda, int ldb, int ldc,
    int bx, int by,
    const float* __restrict__ e0, const float* __restrict__ e1,
    const float* __restrict__ e2, const float* __restrict__ e3,
    unsigned short* __restrict__ lA, unsigned short* __restrict__ lB)
{
  const int m0 = by * 64, n0 = bx * 64;
  const int tid = threadIdx.x, wave = tid >> 6, lane = tid & 63;
  const int wm = (wave >> 1) * 32, wn = (wave & 1) * 32;
  const int srow = lane >> 2;
  const int grow = wave * 16 + srow;
  const int scol = (((lane & 3) ^ ((grow >> 1) & 3))) * 8;
  const int l31 = lane & 31, khi = lane >> 5;
  const int sw2 = (l31 >> 1) & 3;

  f32x16 acc = {};

  for (int k0 = 0; k0 < K; k0 += 64) {
#pragma unroll
    for (int h = 0; h < 2; ++h) {
      gl_lds16(Ab + (long)(m0 + grow) * lda + (k0 + h * 32 + scol), &lA[h * 2048 + wave * 512]);
      gl_lds16(Bb + (long)(n0 + grow) * ldb + (k0 + h * 32 + scol), &lB[h * 2048 + wave * 512]);
    }
    __syncthreads();

    half8 af[4], bfr[4];
#pragma unroll
    for (int ks = 0; ks < 4; ++ks) {
      af[ks] = *(const half8*)&lA[(ks >> 1) * 2048 + (wm + l31) * 32 + ((((ks & 1) * 2 + khi) ^ sw2) * 8)];
      bfr[ks] = *(const half8*)&lB[(ks >> 1) * 2048 + (wn + l31) * 32 + ((((ks & 1) * 2 + khi) ^ sw2) * 8)];
    }
#pragma unroll
    for (int ks = 0; ks < 4; ++ks)
      acc = __builtin_amdgcn_mfma_f32_32x32x16_f16(af[ks], bfr[ks], acc, 0, 0, 0);
    __syncthreads();
  }

  float Ef[4], Df[4];
  if constexpr (EPI == 4) {
    const int col0 = n0 + wn + l31;
#pragma unroll
    for (int j = 0; j < 4; ++j) {
      Ef[j] = e2[j * 1024 + col0];
      Df[j] = e3[j * 1024 + col0];
    }
  }
#pragma unroll
  for (int r = 0; r < 16; ++r) {
    const int row = m0 + wm + khi * 4 + (r & 3) + 8 * (r >> 2);
    const int col = n0 + wn + l31;
    float v = acc[r];
    if constexpr (EPI == 4) {
      const float4 en = *(const float4*)(e0 + (long)row * 4);
      const float4 dp = *(const float4*)(e1 + (long)row * 4);
      v += en.x * Ef[0] + en.y * Ef[1] + en.z * Ef[2] + en.w * Ef[3]
         + dp.x * Df[0] + dp.y * Df[1] + dp.z * Df[2] + dp.w * Df[3];
    }
    const long ci = (long)row * ldc + col;
    if constexpr (sizeof(OutT) == 2) {
      Cb[ci] = (OutT)f2h(v);
    } else {
      Cb[ci] = v;
    }
  }
}

// 128x128-tile GEMM body (4 waves, BK=64, swizzled LDS), fp16 out.
// lA/lB are 2*4096-short scratch. EPI: 0 plain, 1 -> 1.0f - v (div).
template <int EPI>
__device__ __forceinline__ void g128_body(
    const unsigned short* __restrict__ Ab, const unsigned short* __restrict__ Bb,
    unsigned short* __restrict__ Cb, int K, int lda, int ldb, int ldc,
    int bx, int by,
    unsigned short* __restrict__ lA, unsigned short* __restrict__ lB)
{
  const int m0 = by * 128, n0 = bx * 128;
  const int tid = threadIdx.x, wave = tid >> 6, lane = tid & 63;
  const int wm = (wave >> 1) * 64, wn = (wave & 1) * 64;
  const int srow = lane >> 2;
  const int scol = (((lane & 3) ^ ((srow >> 1) & 3))) * 8;
  const int l31 = lane & 31, khi = lane >> 5;
  const int sw2 = (l31 >> 1) & 3;

  f32x16 acc[2][2] = {};

  for (int k0 = 0; k0 < K; k0 += 64) {
#pragma unroll
    for (int h = 0; h < 2; ++h)
#pragma unroll
      for (int t = 0; t < 2; ++t) {
        const int r = wave * 32 + t * 16 + srow;
        gl_lds16(Ab + (long)(m0 + r) * lda + (k0 + h * 32 + scol), &lA[h * 4096 + wave * 1024 + t * 512]);
        gl_lds16(Bb + (long)(n0 + r) * ldb + (k0 + h * 32 + scol), &lB[h * 4096 + wave * 1024 + t * 512]);
      }
    __syncthreads();

    half8 af[2][4], bfr[2][4];
#pragma unroll
    for (int mi = 0; mi < 2; ++mi)
#pragma unroll
      for (int ks = 0; ks < 4; ++ks)
        af[mi][ks] = *(const half8*)&lA[(ks >> 1) * 4096 + (wm + mi * 32 + l31) * 32 + ((((ks & 1) * 2 + khi) ^ sw2) * 8)];
#pragma unroll
    for (int ni = 0; ni < 2; ++ni)
#pragma unroll
      for (int ks = 0; ks < 4; ++ks)
        bfr[ni][ks] = *(const half8*)&lB[(ks >> 1) * 4096 + (wn + ni * 32 + l31) * 32 + ((((ks & 1) * 2 + khi) ^ sw2) * 8)];

#pragma unroll
    for (int ks = 0; ks < 4; ++ks)
#pragma unroll
      for (int mi = 0; mi < 2; ++mi)
#pragma unroll
        for (int ni = 0; ni < 2; ++ni)
          acc[mi][ni] = __builtin_amdgcn_mfma_f32_32x32x16_f16(af[mi][ks], bfr[ni][ks], acc[mi][ni], 0, 0, 0);
    __syncthreads();
  }

#pragma unroll
  for (int mi = 0; mi < 2; ++mi)
#pragma unroll
    for (int ni = 0; ni < 2; ++ni)
#pragma unroll
      for (int r = 0; r < 16; ++r) {
        const int row = m0 + wm + mi * 32 + khi * 4 + (r & 3) + 8 * (r >> 2);
        const int col = n0 + wn + ni * 32 + l31;
        float v = acc[mi][ni][r];
        if constexpr (EPI == 1) v = 1.0f - v;
        Cb[(long)row * ldc + col] = f2h(v);
      }
}

// Mega GEMM launch #1 — all GEMMs that depend only on prep, ALL 128-tile.
// PER-SEGMENT XCD chunking: each segment size is 8*k, so blockIdx's XCD
// round-robin phase is preserved; each XCD gets the same work MIX as natural
// order (balance) plus a contiguous by-band per segment (L2 locality).
//  [0,512)      QK: q=(b&7)*64+(b>>3); z=q>>8, by=(q&255)>>3, bx=q&7
//  [512,768)    Vt: v=(r&7)*32+(r>>3); by=v>>5, bx=v&31
//  [768,1024)   div: d=(r&7)*32+(r>>3); z=d>>6, by=(d&63)>>3, bx=d&7
//  [1024,1088)  WFh: w=(r&7)*8+(r>>3); zj=w>>4, by=(w&15)>>1, bx=w&1
__global__ __launch_bounds__(256) void mega1_kernel(
    const unsigned short* __restrict__ xh, const unsigned short* __restrict__ Wh,
    unsigned short* __restrict__ QKV,
    unsigned short* __restrict__ Vt,
    const unsigned short* __restrict__ xu, unsigned short* __restrict__ divb,
    const unsigned short* __restrict__ WoB, const unsigned short* __restrict__ W2T,
    unsigned short* __restrict__ WFh)
{
  __shared__ __align__(16) unsigned short lbuf[16384];  // 32 KB

  int b = blockIdx.x;
  if (b < 512) {
    const int q = (b & 7) * 64 + (b >> 3);
    const int z = q >> 8, rem = q & 255, by = rem >> 3, bx = rem & 7;
    g128_body<0>(xh, Wh + (long)z * DD * DD, QKV + (long)z * TT * DD,
                 DD, DD, DD, DD, bx, by, lbuf, lbuf + 8192);
    return;
  }
  b -= 512;
  if (b < 256) {
    const int v = (b & 7) * 32 + (b >> 3);
    const int by = v >> 5, bx = v & 31;
    g128_body<0>(Wh + (size_t)2 * DD * DD, xh, Vt, DD, DD, DD, TT, bx, by,
                 lbuf, lbuf + 8192);
    return;
  }
  b -= 256;
  if (b < 256) {
    const int d = (b & 7) * 32 + (b >> 3);
    const int z = d >> 6, r = d & 63, by = r >> 3, bx = r & 7;
    const unsigned short* Xu = xu + (long)z * TBB * DD;
    g128_body<1>(Xu, Xu, divb + (long)z * TBB * TBB,
                 DD, DD, DD, TBB, bx, by, lbuf, lbuf + 8192);
    return;
  }
  b -= 256;
  {
    const int w = (b & 7) * 8 + (b >> 3);
    const int zj = w >> 4, r = w & 15, by = r >> 1, bx = r & 1;
    g128_body<0>(WoB + zj * 256, W2T, WFh + zj * 256,
                 256, DD, 256, DD, bx, by, lbuf, lbuf + 8192);
  }
}

// sim GEMM: C(fp16) = A*B^T + APh, 128x128, flat 1024-grid with XCD swizzle
// (each XCD owns whole gz's -> Q/K slices + APh L2-resident).
__global__ __launch_bounds__(256) void sim_gemm(
    const unsigned short* __restrict__ A, const unsigned short* __restrict__ B,
    unsigned short* __restrict__ C,
    const unsigned short* __restrict__ APh)
{
  __shared__ __align__(16) unsigned short lA[2][4096];
  __shared__ __align__(16) unsigned short lB[2][4096];

  int b = blockIdx.x;
  b = (b & 7) * 128 + (b >> 3);  // 1024 % 8 == 0, bijective
  const int gz = b >> 6, rem = b & 63;
  const int m0 = (rem >> 3) * 128, n0 = (rem & 7) * 128;

  const int zi = gz >> 2, zj = gz & 3;
  const unsigned short* Ab = A + (long)zi * (TBB * DD) + zj * WBB;
  const unsigned short* Bb = B + (long)zi * (TBB * DD) + zj * WBB;
  unsigned short* Cb = C + (long)gz * TBB * TBB;

  const int tid = threadIdx.x, wave = tid >> 6, lane = tid & 63;
  const int wm = (wave >> 1) * 64, wn = (wave & 1) * 64;
  const int srow = lane >> 2;
  const int scol = ((lane & 3) ^ ((srow >> 1) & 3)) * 8;
  const int l31 = lane & 31, khi = lane >> 5;
  const int sw2 = (l31 >> 1) & 3;

  f32x16 acc[2][2] = {};

  for (int k0 = 0; k0 < WBB; k0 += 64) {
#pragma unroll
    for (int h = 0; h < 2; ++h)
#pragma unroll
      for (int t = 0; t < 2; ++t) {
        const int r = wave * 32 + t * 16 + srow;
        gl_lds16(Ab + (long)(m0 + r) * DD + (k0 + h * 32 + scol), &lA[h][wave * 1024 + t * 512]);
        gl_lds16(Bb + (long)(n0 + r) * DD + (k0 + h * 32 + scol), &lB[h][wave * 1024 + t * 512]);
      }
    __syncthreads();

    half8 af[2][4], bfr[2][4];
#pragma unroll
    for (int mi = 0; mi < 2; ++mi)
#pragma unroll
      for (int ks = 0; ks < 4; ++ks)
        af[mi][ks] = *(const half8*)&lA[ks >> 1][(wm + mi * 32 + l31) * 32 + ((((ks & 1) * 2 + khi) ^ sw2) * 8)];
#pragma unroll
    for (int ni = 0; ni < 2; ++ni)
#pragma unroll
      for (int ks = 0; ks < 4; ++ks)
        bfr[ni][ks] = *(const half8*)&lB[ks >> 1][(wn + ni * 32 + l31) * 32 + ((((ks & 1) * 2 + khi) ^ sw2) * 8)];

#pragma unroll
    for (int ks = 0; ks < 4; ++ks)
#pragma unroll
      for (int mi = 0; mi < 2; ++mi)
#pragma unroll
        for (int ni = 0; ni < 2; ++ni)
          acc[mi][ni] = __builtin_amdgcn_mfma_f32_32x32x16_f16(af[mi][ks], bfr[ni][ks], acc[mi][ni], 0, 0, 0);
    __syncthreads();
  }

#pragma unroll
  for (int mi = 0; mi < 2; ++mi)
#pragma unroll
    for (int ni = 0; ni < 2; ++ni)
#pragma unroll
      for (int r = 0; r < 16; ++r) {
        const int row = m0 + wm + mi * 32 + khi * 4 + (r & 3) + 8 * (r >> 2);
        const int col = n0 + wn + ni * 32 + l31;
        Cb[(long)row * TBB + col] = f2h(acc[mi][ni][r] + h2f(APh[(long)row * 1024 + col]));
      }
}

// ctx = (attw * (1+dep[k])) @ Vb, 64x128 tile, flat 516-grid:
// b<4 -> entnorm; else XCD-swizzled work blocks (each XCD owns 2 gz ->
// sim slice + Vt slice L2-resident for the K=1024 re-reads).
__global__ __launch_bounds__(256) void ctx_gemm_s(
    const unsigned short* __restrict__ simh, const float* __restrict__ dep2,
    const float* __restrict__ Brow,
    const unsigned short* __restrict__ Vt, unsigned short* __restrict__ ctxR,
    float* __restrict__ ent2)
{
  const int tid = threadIdx.x;
  int b = blockIdx.x;

  if (b < 4) {
    // entnorm: L1-normalize ent2 over q for i-block b.
    float4 v[4];
    float4 a = {0.f, 0.f, 0.f, 0.f};
#pragma unroll
    for (int p = 0; p < 4; ++p) {
      v[p] = *(const float4*)(ent2 + ((long)b * 1024 + tid + p * 256) * 4);
      a.x += fabsf(v[p].x); a.y += fabsf(v[p].y);
      a.z += fabsf(v[p].z); a.w += fabsf(v[p].w);
    }
    a.x = waveSum(a.x); a.y = waveSum(a.y);
    a.z = waveSum(a.z); a.w = waveSum(a.w);
    __shared__ float red[4][4];
    if ((tid & 63) == 0) {
      const int w = tid >> 6;
      red[w][0] = a.x; red[w][1] = a.y; red[w][2] = a.z; red[w][3] = a.w;
    }
    __syncthreads();
    float4 sc;
    sc.x = 1.f / fmaxf(red[0][0] + red[1][0] + red[2][0] + red[3][0], 1e-12f);
    sc.y = 1.f / fmaxf(red[0][1] + red[1][1] + red[2][1] + red[3][1], 1e-12f);
    sc.z = 1.f / fmaxf(red[0][2] + red[1][2] + red[2][2] + red[3][2], 1e-12f);
    sc.w = 1.f / fmaxf(red[0][3] + red[1][3] + red[2][3] + red[3][3], 1e-12f);
#pragma unroll
    for (int p = 0; p < 4; ++p) {
      float4 o = v[p];
      o.x *= sc.x; o.y *= sc.y; o.z *= sc.z; o.w *= sc.w;
      *(float4*)(ent2 + ((long)b * 1024 + tid + p * 256) * 4) = o;
    }
    return;
  }
  b -= 4;
  b = (b & 7) * 64 + (b >> 3);  // 512 % 8 == 0, bijective
  const int gz = b >> 5, rem = b & 31;
  const int m0 = (rem >> 1) * 64, n0 = (rem & 1) * 128;
  const int zi = gz >> 2, zj = gz & 3;

  __shared__ __align__(16) unsigned short lA[2][2048];
  __shared__ __align__(16) unsigned short lB[2][4096];
  __shared__ __align__(16) unsigned short sDepH[1024];

  const int wave = tid >> 6, lane = tid & 63;
  const int wm = (wave >> 1) * 32, wn0 = (wave & 1) * 64;
  const int srow = lane >> 2;
  const int grow = wave * 16 + srow;
  const int scol = ((lane & 3) ^ ((grow >> 1) & 3)) * 8;
  const int l31 = lane & 31, khi = lane >> 5;
  const int sw2 = (l31 >> 1) & 3;

#pragma unroll
  for (int p = 0; p < 4; ++p)
    sDepH[tid + p * 256] =
        f2h(1.f + dep2[((long)zi * 1024 + tid + p * 256) * 4 + zj]);
  __syncthreads();

  const float B0 = Brow[(long)gz * 1024 + m0 + (tid >> 3)];
  const float B1 = Brow[(long)gz * 1024 + m0 + 32 + (tid >> 3)];

  const unsigned short* Ab = simh + (long)gz * TBB * TBB;
  const unsigned short* Bb = Vt + (long)(zj * 256) * TT + (long)zi * 1024;

  f32x16 acc[2] = {};

  for (int k0 = 0; k0 < 1024; k0 += 64) {
#pragma unroll
    for (int h = 0; h < 2; ++h) {
      gl_lds16(Bb + (long)(n0 + grow) * TT + (k0 + h * 32 + scol), &lB[h][wave * 512]);
      gl_lds16(Bb + (long)(n0 + 64 + grow) * TT + (k0 + h * 32 + scol), &lB[h][2048 + wave * 512]);
    }
#pragma unroll
    for (int h = 0; h < 2; ++h)
#pragma unroll
      for (int p = 0; p < 2; ++p) {
        const int idx = p * 1024 + tid * 4;
        const int row = idx >> 5, col = idx & 31;
        const ushort4 wv = *(const ushort4*)(Ab + (long)(m0 + row) * 1024 + k0 + h * 32 + col);
        const float Bp = p ? B1 : B0;
        half4 ev;
        ev.x = (_Float16)exp2f(fmaf(h2f(wv.x), 1.4426950408889634f, -Bp));
        ev.y = (_Float16)exp2f(fmaf(h2f(wv.y), 1.4426950408889634f, -Bp));
        ev.z = (_Float16)exp2f(fmaf(h2f(wv.z), 1.4426950408889634f, -Bp));
        ev.w = (_Float16)exp2f(fmaf(h2f(wv.w), 1.4426950408889634f, -Bp));
        const half4 dv = *(const half4*)&sDepH[k0 + h * 32 + col];
        half4 pv = ev * dv;
        const int pcol = (((col >> 3) ^ ((row >> 1) & 3)) << 3) | (col & 7);
        *(half4*)&lA[h][row * 32 + pcol] = pv;
      }
    __syncthreads();

    half8 af[4], bfr[2][4];
#pragma unroll
    for (int ks = 0; ks < 4; ++ks) {
      af[ks] = *(const half8*)&lA[ks >> 1][(wm + l31) * 32 + ((((ks & 1) * 2 + khi) ^ sw2) * 8)];
#pragma unroll
      for (int n = 0; n < 2; ++n)
        bfr[n][ks] = *(const half8*)&lB[ks >> 1][(wn0 + n * 32 + l31) * 32 + ((((ks & 1) * 2 + khi) ^ sw2) * 8)];
    }
#pragma unroll
    for (int ks = 0; ks < 4; ++ks)
#pragma unroll
      for (int n = 0; n < 2; ++n)
        acc[n] = __builtin_amdgcn_mfma_f32_32x32x16_f16(af[ks], bfr[n][ks], acc[n], 0, 0, 0);
    __syncthreads();
  }

#pragma unroll
  for (int n = 0; n < 2; ++n)
#pragma unroll
    for (int r = 0; r < 16; ++r) {
      const int row = m0 + wm + khi * 4 + (r & 3) + 8 * (r >> 2);
      const int col = n0 + wn0 + n * 32 + l31;
      ctxR[((long)zi * 1024 + row) * 1024 + zj * 256 + col] = f2h(acc[n][r]);
    }
}

// Final out GEMM: 64-tile, flat 1024-grid with XCD swizzle (WFh L2-resident).
__global__ __launch_bounds__(256) void out_kernel(
    const unsigned short* __restrict__ A, const unsigned short* __restrict__ B,
    float* __restrict__ C,
    const float* __restrict__ e0, const float* __restrict__ e1,
    const float* __restrict__ e2, const float* __restrict__ e3)
{
  __shared__ __align__(16) unsigned short lA[2 * 2048];
  __shared__ __align__(16) unsigned short lB[2 * 2048];
  int b = blockIdx.x;
  b = (b & 7) * 128 + (b >> 3);  // 1024 % 8 == 0, bijective
  g64_body<4, float>(A, B, C, DD, DD, DD, DD, b & 15, b >> 4,
                     e0, e1, e2, e3, lA, lB);
}

// Mega preprocessing kernel — only WIDE-parallel parts (no serial tails).
__global__ __launch_bounds__(256) void prep_kernel(
    const float* __restrict__ x, const float* __restrict__ Wq,
    const float* __restrict__ Wk, const float* __restrict__ Wv,
    const float* __restrict__ Wo, const float* __restrict__ W2,
    unsigned short* __restrict__ xh, unsigned short* __restrict__ xu,
    unsigned short* __restrict__ Wh, unsigned short* __restrict__ APh,
    unsigned short* __restrict__ WoB, unsigned short* __restrict__ W2T,
    float* __restrict__ Efold, float* __restrict__ Dfold)
{
  __shared__ float red[4];
  int b = blockIdx.x;
  const int tid = threadIdx.x;

  if (b < 4096) {
    const int t = b;
    const float4 v = *((const float4*)(x + (long)t * DD) + tid);
    float ss = v.x * v.x + v.y * v.y + v.z * v.z + v.w * v.w;
    ss = waveSum(ss);
    if ((tid & 63) == 0) red[tid >> 6] = ss;
    __syncthreads();
    const float tot = red[0] + red[1] + red[2] + red[3];
    const float inv = 1.f / fmaxf(sqrtf(tot), 1e-12f);
    ushort4 h, u;
    h.x = f2h(v.x); h.y = f2h(v.y); h.z = f2h(v.z); h.w = f2h(v.w);
    u.x = f2h(v.x * inv); u.y = f2h(v.y * inv); u.z = f2h(v.z * inv); u.w = f2h(v.w * inv);
    *((ushort4*)(xh + (long)t * DD) + tid) = h;
    *((ushort4*)(xu + (long)t * DD) + tid) = u;
    return;
  }
  b -= 4096;
  if (b < 3072) {
    const long idx4 = ((long)b * 256 + tid) * 4;
    const int which = (int)(idx4 >> 20);
    const long loc = idx4 & ((1L << 20) - 1);
    const float* src = (which == 0) ? Wq : ((which == 1) ? Wk : Wv);
    const float4 v = *(const float4*)(src + loc);
    ushort4 h;
    h.x = f2h(v.x); h.y = f2h(v.y); h.z = f2h(v.z); h.w = f2h(v.w);
    *(ushort4*)(Wh + idx4) = h;
    return;
  }
  b -= 3072;
  if (b < 1024) {
    const int p = b;
#pragma unroll
    for (int t = 0; t < 2; ++t) {
      const int pr = tid + t * 256;
      const float e = (float)pr * (1.0f / 512.0f);
      const float ang = (float)p * exp2f(e * -13.287712379549449f);
      float s, c;
      sincosf(ang, &s, &c);
      ushort2 o;
      o.x = f2h(s); o.y = f2h(c);
      *(ushort2*)(APh + (long)p * 1024 + 2 * pr) = o;
    }
    return;
  }
  b -= 1024;
  if (b < 1024) {
    const long idx4 = ((long)b * 256 + tid) * 4;
    const float4 v = *(const float4*)(Wo + idx4);
    ushort4 h;
    h.x = f2h(v.x); h.y = f2h(v.y); h.z = f2h(v.z); h.w = f2h(v.w);
    *(ushort4*)(WoB + idx4) = h;
    return;
  }
  b -= 1024;
  if (b < 256) {
    const int w = b;
    W2T[tid * 256 + w] = f2h(W2[w * 258 + tid]);
    return;
  }
  b -= 256;
  {
    // Efold/Dfold: wave-parallel over K (lane=w), butterfly reduce.
    const int wave = tid >> 6, lane = tid & 63;
    float we[4], wd[4];
#pragma unroll
    for (int u = 0; u < 4; ++u) {
      we[u] = W2[(lane * 4 + u) * 258 + 256];
      wd[u] = W2[(lane * 4 + u) * 258 + 257];
    }
    for (int i = 0; i < 16; ++i) {
      const int pidx = (b * 4 + wave) * 16 + i;  // 0..4095
      const int j = pidx >> 10, d = pidx & 1023;
      const float4 v = *(const float4*)(Wo + (long)d * 1024 + j * 256 + lane * 4);
      float se = v.x * we[0] + v.y * we[1] + v.z * we[2] + v.w * we[3];
      float sd = v.x * wd[0] + v.y * wd[1] + v.z * wd[2] + v.w * wd[3];
      se = bSum(se);
      sd = bSum(sd);
      if (lane == 0) {
        Efold[j * 1024 + d] = se;
        Dfold[j * 1024 + d] = sd;
      }
    }
  }
}

// Wave-per-row stats, div row shared across the 4 j's of block-row bi.
__global__ __launch_bounds__(256) void stats_kernel(
    const unsigned short* __restrict__ sim, const unsigned short* __restrict__ divb,
    float* __restrict__ dep2, float* __restrict__ ent2,
    float* __restrict__ Brow)
{
  __shared__ __align__(16) unsigned short sDiv[1024];
  const int q = blockIdx.x, bi = blockIdx.y;
  const int tid = threadIdx.x;
  const int wave = tid >> 6, lane = tid & 63;

  *(ushort4*)&sDiv[tid * 4] =
      *(const ushort4*)(divb + ((long)bi * TBB + q) * TBB + tid * 4);
  __syncthreads();

  const int gz = bi * 4 + wave;
  const unsigned short* srow = sim + ((long)gz * TBB + q) * TBB;
  float s[16], d[16];
#pragma unroll
  for (int u = 0; u < 4; ++u) {
    const ushort4 sv = *(const ushort4*)(srow + u * 256 + lane * 4);
    const ushort4 dv = *(const ushort4*)&sDiv[u * 256 + lane * 4];
    s[u * 4 + 0] = h2f(sv.x); s[u * 4 + 1] = h2f(sv.y);
    s[u * 4 + 2] = h2f(sv.z); s[u * 4 + 3] = h2f(sv.w);
    d[u * 4 + 0] = h2f(dv.x); d[u * 4 + 1] = h2f(dv.y);
    d[u * 4 + 2] = h2f(dv.z); d[u * 4 + 3] = h2f(dv.w);
  }
  float m = s[0];
#pragma unroll
  for (int i = 1; i < 16; ++i) m = fmaxf(m, s[i]);
  m = bMax(m);
  const float mB = m * 1.4426950408889634f;
  float l = 0.f, ss = 0.f, dn = 0.f, ds = 0.f;
#pragma unroll
  for (int i = 0; i < 16; ++i) {
    const float e = exp2f(fmaf(s[i], 1.4426950408889634f, -mB));
    l += e; ss += e * s[i]; dn += e * d[i]; ds += d[i];
  }
  l = bSum(l); ss = bSum(ss); dn = bSum(dn); ds = bSum(ds);
  if (lane == 0) {
    const float Li = 1.f / l;
    const float lnL = logf(l);
    const long o2 = ((long)bi * 1024 + q) * 4 + wave;
    dep2[o2] = (dn * Li) / ds;
    ent2[o2] = (m + lnL - ss * Li) * 0.14426950408889634f;  // 1/ln(1024)
    Brow[(long)gz * TBB + q] = (m + lnL) * 1.4426950408889634f;
  }
}

extern "C" void kernel_launch(void* const* d_in, const int* in_sizes, int n_in,
                              void* d_out, int out_size, void* d_ws, size_t ws_size,
                              hipStream_t stream)
{
  const float* x  = (const float*)d_in[0];
  const float* Wq = (const float*)d_in[1];
  const float* Wk = (const float*)d_in[2];
  const float* Wv = (const float*)d_in[3];
  const float* Wo = (const float*)d_in[4];
  const float* W2 = (const float*)d_in[5];

  char* ws = (char*)d_ws;
  size_t off = 0;
  auto take = [&](size_t bytes) -> void* {
    void* p = ws + off;
    off += (bytes + 255) & ~(size_t)255;
    return p;
  };
  unsigned short* QKV = (unsigned short*)take((size_t)2 * TT * DD * 2);  // Q,K
  unsigned short* xh  = (unsigned short*)take((size_t)TT * DD * 2);
  unsigned short* xu  = (unsigned short*)take((size_t)TT * DD * 2);
  unsigned short* Wh  = (unsigned short*)take((size_t)3 * DD * DD * 2);
  unsigned short* WoB = (unsigned short*)take((size_t)DD * DD * 2);
  unsigned short* W2T = (unsigned short*)take((size_t)256 * 256 * 2);
  unsigned short* WFh = (unsigned short*)take((size_t)DD * DD * 2);
  float* Efold = (float*)take((size_t)4 * DD * 4);
  float* Dfold = (float*)take((size_t)4 * DD * 4);
  unsigned short* APh = (unsigned short*)take((size_t)TBB * TBB * 2);
  unsigned short* divb = (unsigned short*)take((size_t)4 * TBB * TBB * 2);
  unsigned short* Vt = (unsigned short*)take((size_t)DD * TT * 2);
  unsigned short* simh = (unsigned short*)take((size_t)16 * TBB * TBB * 2);
  float* dep2 = (float*)take((size_t)TT * 4 * 4);
  float* ent2 = (float*)take((size_t)TT * 4 * 4);
  float* Brow = (float*)take((size_t)16 * TBB * 4);
  unsigned short* ctxR = (unsigned short*)take((size_t)TT * DD * 2);
  (void)ws_size; (void)in_sizes; (void)n_in; (void)out_size;

  // 1) wide-parallel preprocessing
  prep_kernel<<<9536, 256, 0, stream>>>(x, Wq, Wk, Wv, Wo, W2,
                                        xh, xu, Wh, APh, WoB, W2T, Efold, Dfold);

  // 2) ALL prep-dependent GEMMs, all 128-tile, per-segment XCD chunking
  mega1_kernel<<<1088, 256, 0, stream>>>(
      xh, Wh, QKV, Vt, xu, divb, WoB, W2T, WFh);

  const unsigned short* Qh = QKV;
  const unsigned short* Kh = QKV + (size_t)TT * DD;

  // 3) sim = Qb @ Kb^T + APh (fp16 out), flat grid + XCD swizzle
  sim_gemm<<<1024, 256, 0, stream>>>(Qh, Kh, simh, APh);

  // 4) stats: block=(q,bi), wave=j; div row staged once in LDS
  stats_kernel<<<dim3(TBB, 4), 256, 0, stream>>>(simh, divb, dep2, ent2, Brow);

  // 5) ctxR + entnorm side-blocks, flat grid + XCD swizzle
  ctx_gemm_s<<<516, 256, 0, stream>>>(simh, dep2, Brow, Vt, ctxR, ent2);

  // 6) out = ctxR @ WFh^T + rank-8 ent/dep epilogue, flat grid + XCD swizzle
  out_kernel<<<1024, 256, 0, stream>>>(
      ctxR, WFh, (float*)d_out, ent2, dep2, Efold, Dfold);
}

// Round 12
// 218.364 us; speedup vs baseline: 1.1073x; 1.0024x over previous
//
#include <hip/hip_runtime.h>
#include <hip/hip_bf16.h>

#define TT 4096
#define DD 1024
#define TBB 1024
#define WBB 256

typedef __attribute__((ext_vector_type(8))) _Float16 half8;
typedef __attribute__((ext_vector_type(4))) _Float16 half4;
typedef __attribute__((ext_vector_type(16))) float f32x16;

__device__ __forceinline__ unsigned short f2h(float v) {
  _Float16 h = (_Float16)v;
  return *reinterpret_cast<unsigned short*>(&h);
}
__device__ __forceinline__ float h2f(unsigned short u) {
  _Float16 h = *reinterpret_cast<_Float16*>(&u);
  return (float)h;
}

__device__ __forceinline__ void gl_lds16(const unsigned short* g, unsigned short* l) {
  __builtin_amdgcn_global_load_lds(
      (const __attribute__((address_space(1))) void*)(unsigned long long)(g),
      (__attribute__((address_space(3))) void*)(unsigned long long)(l),
      16, 0, 0);
}

__device__ __forceinline__ float waveSum(float v) {
#pragma unroll
  for (int o = 32; o > 0; o >>= 1) v += __shfl_down(v, o, 64);
  return v;
}
__device__ __forceinline__ float bSum(float v) {
#pragma unroll
  for (int o = 32; o > 0; o >>= 1) v += __shfl_xor(v, o, 64);
  return v;
}
__device__ __forceinline__ float bMax(float v) {
#pragma unroll
  for (int o = 32; o > 0; o >>= 1) v = fmaxf(v, __shfl_xor(v, o, 64));
  return v;
}

// 128x128-tile GEMM body (4 waves, BK=64, swizzled LDS).
// lA/lB are 2*4096-short scratch.
// EPI: 0 plain fp16, 1 -> 1.0f - v fp16 (div), 4 -> rank-8 ent/dep + f32 out.
template <int EPI, typename OutT>
__device__ __forceinline__ void g128_body(
    const unsigned short* __restrict__ Ab, const unsigned short* __restrict__ Bb,
    OutT* __restrict__ Cb, int K, int lda, int ldb, int ldc,
    int bx, int by,
    const float* __restrict__ e0, const float* __restrict__ e1,
    const float* __restrict__ e2, const float* __restrict__ e3,
    unsigned short* __restrict__ lA, unsigned short* __restrict__ lB)
{
  const int m0 = by * 128, n0 = bx * 128;
  const int tid = threadIdx.x, wave = tid >> 6, lane = tid & 63;
  const int wm = (wave >> 1) * 64, wn = (wave & 1) * 64;
  const int srow = lane >> 2;
  const int scol = (((lane & 3) ^ ((srow >> 1) & 3))) * 8;
  const int l31 = lane & 31, khi = lane >> 5;
  const int sw2 = (l31 >> 1) & 3;

  f32x16 acc[2][2] = {};

  for (int k0 = 0; k0 < K; k0 += 64) {
#pragma unroll
    for (int h = 0; h < 2; ++h)
#pragma unroll
      for (int t = 0; t < 2; ++t) {
        const int r = wave * 32 + t * 16 + srow;
        gl_lds16(Ab + (long)(m0 + r) * lda + (k0 + h * 32 + scol), &lA[h * 4096 + wave * 1024 + t * 512]);
        gl_lds16(Bb + (long)(n0 + r) * ldb + (k0 + h * 32 + scol), &lB[h * 4096 + wave * 1024 + t * 512]);
      }
    __syncthreads();

    half8 af[2][4], bfr[2][4];
#pragma unroll
    for (int mi = 0; mi < 2; ++mi)
#pragma unroll
      for (int ks = 0; ks < 4; ++ks)
        af[mi][ks] = *(const half8*)&lA[(ks >> 1) * 4096 + (wm + mi * 32 + l31) * 32 + ((((ks & 1) * 2 + khi) ^ sw2) * 8)];
#pragma unroll
    for (int ni = 0; ni < 2; ++ni)
#pragma unroll
      for (int ks = 0; ks < 4; ++ks)
        bfr[ni][ks] = *(const half8*)&lB[(ks >> 1) * 4096 + (wn + ni * 32 + l31) * 32 + ((((ks & 1) * 2 + khi) ^ sw2) * 8)];

#pragma unroll
    for (int ks = 0; ks < 4; ++ks)
#pragma unroll
      for (int mi = 0; mi < 2; ++mi)
#pragma unroll
        for (int ni = 0; ni < 2; ++ni)
          acc[mi][ni] = __builtin_amdgcn_mfma_f32_32x32x16_f16(af[mi][ks], bfr[ni][ks], acc[mi][ni], 0, 0, 0);
    __syncthreads();
  }

  float Ef[2][4], Df[2][4];
  if constexpr (EPI == 4) {
#pragma unroll
    for (int ni = 0; ni < 2; ++ni) {
      const int col0 = n0 + wn + ni * 32 + l31;
#pragma unroll
      for (int j = 0; j < 4; ++j) {
        Ef[ni][j] = e2[j * 1024 + col0];
        Df[ni][j] = e3[j * 1024 + col0];
      }
    }
  }
#pragma unroll
  for (int mi = 0; mi < 2; ++mi)
#pragma unroll
    for (int r = 0; r < 16; ++r) {
      const int row = m0 + wm + mi * 32 + khi * 4 + (r & 3) + 8 * (r >> 2);
      float4 en, dp;
      if constexpr (EPI == 4) {
        en = *(const float4*)(e0 + (long)row * 4);
        dp = *(const float4*)(e1 + (long)row * 4);
      }
#pragma unroll
      for (int ni = 0; ni < 2; ++ni) {
        const int col = n0 + wn + ni * 32 + l31;
        float v = acc[mi][ni][r];
        if constexpr (EPI == 1) v = 1.0f - v;
        if constexpr (EPI == 4)
          v += en.x * Ef[ni][0] + en.y * Ef[ni][1] + en.z * Ef[ni][2] + en.w * Ef[ni][3]
             + dp.x * Df[ni][0] + dp.y * Df[ni][1] + dp.z * Df[ni][2] + dp.w * Df[ni][3];
        const long ci = (long)row * ldc + col;
        if constexpr (sizeof(OutT) == 2) {
          Cb[ci] = (OutT)f2h(v);
        } else {
          Cb[ci] = v;
        }
      }
    }
}

// Mega GEMM launch #1 — all GEMMs that depend only on prep, ALL 128-tile.
// PER-SEGMENT XCD chunking (r11-verified: producer->consumer L2 affinity with
// sim/ctx swizzles outweighs mega1's own slowdown).
__global__ __launch_bounds__(256) void mega1_kernel(
    const unsigned short* __restrict__ xh, const unsigned short* __restrict__ Wh,
    unsigned short* __restrict__ QKV,
    unsigned short* __restrict__ Vt,
    const unsigned short* __restrict__ xu, unsigned short* __restrict__ divb,
    const unsigned short* __restrict__ WoB, const unsigned short* __restrict__ W2T,
    unsigned short* __restrict__ WFh)
{
  __shared__ __align__(16) unsigned short lbuf[16384];  // 32 KB

  int b = blockIdx.x;
  if (b < 512) {
    const int q = (b & 7) * 64 + (b >> 3);
    const int z = q >> 8, rem = q & 255, by = rem >> 3, bx = rem & 7;
    g128_body<0, unsigned short>(xh, Wh + (long)z * DD * DD, QKV + (long)z * TT * DD,
                 DD, DD, DD, DD, bx, by,
                 nullptr, nullptr, nullptr, nullptr, lbuf, lbuf + 8192);
    return;
  }
  b -= 512;
  if (b < 256) {
    const int v = (b & 7) * 32 + (b >> 3);
    const int by = v >> 5, bx = v & 31;
    g128_body<0, unsigned short>(Wh + (size_t)2 * DD * DD, xh, Vt, DD, DD, DD, TT, bx, by,
                 nullptr, nullptr, nullptr, nullptr, lbuf, lbuf + 8192);
    return;
  }
  b -= 256;
  if (b < 256) {
    const int d = (b & 7) * 32 + (b >> 3);
    const int z = d >> 6, r = d & 63, by = r >> 3, bx = r & 7;
    const unsigned short* Xu = xu + (long)z * TBB * DD;
    g128_body<1, unsigned short>(Xu, Xu, divb + (long)z * TBB * TBB,
                 DD, DD, DD, TBB, bx, by,
                 nullptr, nullptr, nullptr, nullptr, lbuf, lbuf + 8192);
    return;
  }
  b -= 256;
  {
    const int w = (b & 7) * 8 + (b >> 3);
    const int zj = w >> 4, r = w & 15, by = r >> 1, bx = r & 1;
    g128_body<0, unsigned short>(WoB + zj * 256, W2T, WFh + zj * 256,
                 256, DD, 256, DD, bx, by,
                 nullptr, nullptr, nullptr, nullptr, lbuf, lbuf + 8192);
  }
}

// sim GEMM: C(fp16) = A*B^T + APh, 128x128, flat 1024-grid with XCD swizzle
// (each XCD owns whole gz's -> Q/K slices + APh L2-resident; matches mega1's
// QK producer bands).
__global__ __launch_bounds__(256) void sim_gemm(
    const unsigned short* __restrict__ A, const unsigned short* __restrict__ B,
    unsigned short* __restrict__ C,
    const unsigned short* __restrict__ APh)
{
  __shared__ __align__(16) unsigned short lA[2][4096];
  __shared__ __align__(16) unsigned short lB[2][4096];

  int b = blockIdx.x;
  b = (b & 7) * 128 + (b >> 3);  // 1024 % 8 == 0, bijective
  const int gz = b >> 6, rem = b & 63;
  const int m0 = (rem >> 3) * 128, n0 = (rem & 7) * 128;

  const int zi = gz >> 2, zj = gz & 3;
  const unsigned short* Ab = A + (long)zi * (TBB * DD) + zj * WBB;
  const unsigned short* Bb = B + (long)zi * (TBB * DD) + zj * WBB;
  unsigned short* Cb = C + (long)gz * TBB * TBB;

  const int tid = threadIdx.x, wave = tid >> 6, lane = tid & 63;
  const int wm = (wave >> 1) * 64, wn = (wave & 1) * 64;
  const int srow = lane >> 2;
  const int scol = ((lane & 3) ^ ((srow >> 1) & 3)) * 8;
  const int l31 = lane & 31, khi = lane >> 5;
  const int sw2 = (l31 >> 1) & 3;

  f32x16 acc[2][2] = {};

  for (int k0 = 0; k0 < WBB; k0 += 64) {
#pragma unroll
    for (int h = 0; h < 2; ++h)
#pragma unroll
      for (int t = 0; t < 2; ++t) {
        const int r = wave * 32 + t * 16 + srow;
        gl_lds16(Ab + (long)(m0 + r) * DD + (k0 + h * 32 + scol), &lA[h][wave * 1024 + t * 512]);
        gl_lds16(Bb + (long)(n0 + r) * DD + (k0 + h * 32 + scol), &lB[h][wave * 1024 + t * 512]);
      }
    __syncthreads();

    half8 af[2][4], bfr[2][4];
#pragma unroll
    for (int mi = 0; mi < 2; ++mi)
#pragma unroll
      for (int ks = 0; ks < 4; ++ks)
        af[mi][ks] = *(const half8*)&lA[ks >> 1][(wm + mi * 32 + l31) * 32 + ((((ks & 1) * 2 + khi) ^ sw2) * 8)];
#pragma unroll
    for (int ni = 0; ni < 2; ++ni)
#pragma unroll
      for (int ks = 0; ks < 4; ++ks)
        bfr[ni][ks] = *(const half8*)&lB[ks >> 1][(wn + ni * 32 + l31) * 32 + ((((ks & 1) * 2 + khi) ^ sw2) * 8)];

#pragma unroll
    for (int ks = 0; ks < 4; ++ks)
#pragma unroll
      for (int mi = 0; mi < 2; ++mi)
#pragma unroll
        for (int ni = 0; ni < 2; ++ni)
          acc[mi][ni] = __builtin_amdgcn_mfma_f32_32x32x16_f16(af[mi][ks], bfr[ni][ks], acc[mi][ni], 0, 0, 0);
    __syncthreads();
  }

#pragma unroll
  for (int mi = 0; mi < 2; ++mi)
#pragma unroll
    for (int ni = 0; ni < 2; ++ni)
#pragma unroll
      for (int r = 0; r < 16; ++r) {
        const int row = m0 + wm + mi * 32 + khi * 4 + (r & 3) + 8 * (r >> 2);
        const int col = n0 + wn + ni * 32 + l31;
        Cb[(long)row * TBB + col] = f2h(acc[mi][ni][r] + h2f(APh[(long)row * 1024 + col]));
      }
}

// ctx = (attw * (1+dep[k])) @ Vb, 64x128 tile, flat 516-grid:
// b<4 -> entnorm; else XCD-swizzled work blocks (gz-aligned with sim producer).
__global__ __launch_bounds__(256) void ctx_gemm_s(
    const unsigned short* __restrict__ simh, const float* __restrict__ dep2,
    const float* __restrict__ Brow,
    const unsigned short* __restrict__ Vt, unsigned short* __restrict__ ctxR,
    float* __restrict__ ent2)
{
  const int tid = threadIdx.x;
  int b = blockIdx.x;

  if (b < 4) {
    // entnorm: L1-normalize ent2 over q for i-block b.
    float4 v[4];
    float4 a = {0.f, 0.f, 0.f, 0.f};
#pragma unroll
    for (int p = 0; p < 4; ++p) {
      v[p] = *(const float4*)(ent2 + ((long)b * 1024 + tid + p * 256) * 4);
      a.x += fabsf(v[p].x); a.y += fabsf(v[p].y);
      a.z += fabsf(v[p].z); a.w += fabsf(v[p].w);
    }
    a.x = waveSum(a.x); a.y = waveSum(a.y);
    a.z = waveSum(a.z); a.w = waveSum(a.w);
    __shared__ float red[4][4];
    if ((tid & 63) == 0) {
      const int w = tid >> 6;
      red[w][0] = a.x; red[w][1] = a.y; red[w][2] = a.z; red[w][3] = a.w;
    }
    __syncthreads();
    float4 sc;
    sc.x = 1.f / fmaxf(red[0][0] + red[1][0] + red[2][0] + red[3][0], 1e-12f);
    sc.y = 1.f / fmaxf(red[0][1] + red[1][1] + red[2][1] + red[3][1], 1e-12f);
    sc.z = 1.f / fmaxf(red[0][2] + red[1][2] + red[2][2] + red[3][2], 1e-12f);
    sc.w = 1.f / fmaxf(red[0][3] + red[1][3] + red[2][3] + red[3][3], 1e-12f);
#pragma unroll
    for (int p = 0; p < 4; ++p) {
      float4 o = v[p];
      o.x *= sc.x; o.y *= sc.y; o.z *= sc.z; o.w *= sc.w;
      *(float4*)(ent2 + ((long)b * 1024 + tid + p * 256) * 4) = o;
    }
    return;
  }
  b -= 4;
  b = (b & 7) * 64 + (b >> 3);  // 512 % 8 == 0, bijective
  const int gz = b >> 5, rem = b & 31;
  const int m0 = (rem >> 1) * 64, n0 = (rem & 1) * 128;
  const int zi = gz >> 2, zj = gz & 3;

  __shared__ __align__(16) unsigned short lA[2][2048];
  __shared__ __align__(16) unsigned short lB[2][4096];
  __shared__ __align__(16) unsigned short sDepH[1024];

  const int wave = tid >> 6, lane = tid & 63;
  const int wm = (wave >> 1) * 32, wn0 = (wave & 1) * 64;
  const int srow = lane >> 2;
  const int grow = wave * 16 + srow;
  const int scol = ((lane & 3) ^ ((grow >> 1) & 3)) * 8;
  const int l31 = lane & 31, khi = lane >> 5;
  const int sw2 = (l31 >> 1) & 3;

#pragma unroll
  for (int p = 0; p < 4; ++p)
    sDepH[tid + p * 256] =
        f2h(1.f + dep2[((long)zi * 1024 + tid + p * 256) * 4 + zj]);
  __syncthreads();

  const float B0 = Brow[(long)gz * 1024 + m0 + (tid >> 3)];
  const float B1 = Brow[(long)gz * 1024 + m0 + 32 + (tid >> 3)];

  const unsigned short* Ab = simh + (long)gz * TBB * TBB;
  const unsigned short* Bb = Vt + (long)(zj * 256) * TT + (long)zi * 1024;

  f32x16 acc[2] = {};

  for (int k0 = 0; k0 < 1024; k0 += 64) {
#pragma unroll
    for (int h = 0; h < 2; ++h) {
      gl_lds16(Bb + (long)(n0 + grow) * TT + (k0 + h * 32 + scol), &lB[h][wave * 512]);
      gl_lds16(Bb + (long)(n0 + 64 + grow) * TT + (k0 + h * 32 + scol), &lB[h][2048 + wave * 512]);
    }
#pragma unroll
    for (int h = 0; h < 2; ++h)
#pragma unroll
      for (int p = 0; p < 2; ++p) {
        const int idx = p * 1024 + tid * 4;
        const int row = idx >> 5, col = idx & 31;
        const ushort4 wv = *(const ushort4*)(Ab + (long)(m0 + row) * 1024 + k0 + h * 32 + col);
        const float Bp = p ? B1 : B0;
        half4 ev;
        ev.x = (_Float16)exp2f(fmaf(h2f(wv.x), 1.4426950408889634f, -Bp));
        ev.y = (_Float16)exp2f(fmaf(h2f(wv.y), 1.4426950408889634f, -Bp));
        ev.z = (_Float16)exp2f(fmaf(h2f(wv.z), 1.4426950408889634f, -Bp));
        ev.w = (_Float16)exp2f(fmaf(h2f(wv.w), 1.4426950408889634f, -Bp));
        const half4 dv = *(const half4*)&sDepH[k0 + h * 32 + col];
        half4 pv = ev * dv;
        const int pcol = (((col >> 3) ^ ((row >> 1) & 3)) << 3) | (col & 7);
        *(half4*)&lA[h][row * 32 + pcol] = pv;
      }
    __syncthreads();

    half8 af[4], bfr[2][4];
#pragma unroll
    for (int ks = 0; ks < 4; ++ks) {
      af[ks] = *(const half8*)&lA[ks >> 1][(wm + l31) * 32 + ((((ks & 1) * 2 + khi) ^ sw2) * 8)];
#pragma unroll
      for (int n = 0; n < 2; ++n)
        bfr[n][ks] = *(const half8*)&lB[ks >> 1][(wn0 + n * 32 + l31) * 32 + ((((ks & 1) * 2 + khi) ^ sw2) * 8)];
    }
#pragma unroll
    for (int ks = 0; ks < 4; ++ks)
#pragma unroll
      for (int n = 0; n < 2; ++n)
        acc[n] = __builtin_amdgcn_mfma_f32_32x32x16_f16(af[ks], bfr[n][ks], acc[n], 0, 0, 0);
    __syncthreads();
  }

#pragma unroll
  for (int n = 0; n < 2; ++n)
#pragma unroll
    for (int r = 0; r < 16; ++r) {
      const int row = m0 + wm + khi * 4 + (r & 3) + 8 * (r >> 2);
      const int col = n0 + wn0 + n * 32 + l31;
      ctxR[((long)zi * 1024 + row) * 1024 + zj * 256 + col] = f2h(acc[n][r]);
    }
}

// Final out GEMM: 128-tile, grid 256 = exactly 1 block/CU, zero tail.
// XCD swizzle: XCD k owns row band [512k,512k+512) (~50% ctxR affinity).
__global__ __launch_bounds__(256) void out_kernel(
    const unsigned short* __restrict__ A, const unsigned short* __restrict__ B,
    float* __restrict__ C,
    const float* __restrict__ e0, const float* __restrict__ e1,
    const float* __restrict__ e2, const float* __restrict__ e3)
{
  __shared__ __align__(16) unsigned short lbuf[16384];
  int b = blockIdx.x;
  b = (b & 7) * 32 + (b >> 3);  // 256 % 8 == 0, bijective
  g128_body<4, float>(A, B, C, DD, DD, DD, DD, b & 7, b >> 3,
                      e0, e1, e2, e3, lbuf, lbuf + 8192);
}

// Mega preprocessing kernel — only WIDE-parallel parts (no serial tails).
__global__ __launch_bounds__(256) void prep_kernel(
    const float* __restrict__ x, const float* __restrict__ Wq,
    const float* __restrict__ Wk, const float* __restrict__ Wv,
    const float* __restrict__ Wo, const float* __restrict__ W2,
    unsigned short* __restrict__ xh, unsigned short* __restrict__ xu,
    unsigned short* __restrict__ Wh, unsigned short* __restrict__ APh,
    unsigned short* __restrict__ WoB, unsigned short* __restrict__ W2T,
    float* __restrict__ Efold, float* __restrict__ Dfold)
{
  __shared__ float red[4];
  int b = blockIdx.x;
  const int tid = threadIdx.x;

  if (b < 4096) {
    const int t = b;
    const float4 v = *((const float4*)(x + (long)t * DD) + tid);
    float ss = v.x * v.x + v.y * v.y + v.z * v.z + v.w * v.w;
    ss = waveSum(ss);
    if ((tid & 63) == 0) red[tid >> 6] = ss;
    __syncthreads();
    const float tot = red[0] + red[1] + red[2] + red[3];
    const float inv = 1.f / fmaxf(sqrtf(tot), 1e-12f);
    ushort4 h, u;
    h.x = f2h(v.x); h.y = f2h(v.y); h.z = f2h(v.z); h.w = f2h(v.w);
    u.x = f2h(v.x * inv); u.y = f2h(v.y * inv); u.z = f2h(v.z * inv); u.w = f2h(v.w * inv);
    *((ushort4*)(xh + (long)t * DD) + tid) = h;
    *((ushort4*)(xu + (long)t * DD) + tid) = u;
    return;
  }
  b -= 4096;
  if (b < 3072) {
    const long idx4 = ((long)b * 256 + tid) * 4;
    const int which = (int)(idx4 >> 20);
    const long loc = idx4 & ((1L << 20) - 1);
    const float* src = (which == 0) ? Wq : ((which == 1) ? Wk : Wv);
    const float4 v = *(const float4*)(src + loc);
    ushort4 h;
    h.x = f2h(v.x); h.y = f2h(v.y); h.z = f2h(v.z); h.w = f2h(v.w);
    *(ushort4*)(Wh + idx4) = h;
    return;
  }
  b -= 3072;
  if (b < 1024) {
    const int p = b;
#pragma unroll
    for (int t = 0; t < 2; ++t) {
      const int pr = tid + t * 256;
      const float e = (float)pr * (1.0f / 512.0f);
      const float ang = (float)p * exp2f(e * -13.287712379549449f);
      float s, c;
      sincosf(ang, &s, &c);
      ushort2 o;
      o.x = f2h(s); o.y = f2h(c);
      *(ushort2*)(APh + (long)p * 1024 + 2 * pr) = o;
    }
    return;
  }
  b -= 1024;
  if (b < 1024) {
    const long idx4 = ((long)b * 256 + tid) * 4;
    const float4 v = *(const float4*)(Wo + idx4);
    ushort4 h;
    h.x = f2h(v.x); h.y = f2h(v.y); h.z = f2h(v.z); h.w = f2h(v.w);
    *(ushort4*)(WoB + idx4) = h;
    return;
  }
  b -= 1024;
  if (b < 256) {
    const int w = b;
    W2T[tid * 256 + w] = f2h(W2[w * 258 + tid]);
    return;
  }
  b -= 256;
  {
    // Efold/Dfold: wave-parallel over K (lane=w), butterfly reduce.
    const int wave = tid >> 6, lane = tid & 63;
    float we[4], wd[4];
#pragma unroll
    for (int u = 0; u < 4; ++u) {
      we[u] = W2[(lane * 4 + u) * 258 + 256];
      wd[u] = W2[(lane * 4 + u) * 258 + 257];
    }
    for (int i = 0; i < 16; ++i) {
      const int pidx = (b * 4 + wave) * 16 + i;  // 0..4095
      const int j = pidx >> 10, d = pidx & 1023;
      const float4 v = *(const float4*)(Wo + (long)d * 1024 + j * 256 + lane * 4);
      float se = v.x * we[0] + v.y * we[1] + v.z * we[2] + v.w * we[3];
      float sd = v.x * wd[0] + v.y * wd[1] + v.z * wd[2] + v.w * wd[3];
      se = bSum(se);
      sd = bSum(sd);
      if (lane == 0) {
        Efold[j * 1024 + d] = se;
        Dfold[j * 1024 + d] = sd;
      }
    }
  }
}

// Wave-per-row stats, div row shared across the 4 j's of block-row bi.
// Flat 4096-grid with XCD affinity: XCD x handles bi=x>>1, q=(x&1)*512+i
// -> div rows 100% produced by this XCD-pair (mega1 div bands), sim gz
// 4bi..4bi+3 50% produced here (sim's gz swizzle). Balanced: 512 blocks/XCD.
__global__ __launch_bounds__(256) void stats_kernel(
    const unsigned short* __restrict__ sim, const unsigned short* __restrict__ divb,
    float* __restrict__ dep2, float* __restrict__ ent2,
    float* __restrict__ Brow)
{
  __shared__ __align__(16) unsigned short sDiv[1024];
  const int b = blockIdx.x;
  const int x = b & 7, i = b >> 3;
  const int bi = x >> 1, q = (x & 1) * 512 + i;
  const int tid = threadIdx.x;
  const int wave = tid >> 6, lane = tid & 63;

  *(ushort4*)&sDiv[tid * 4] =
      *(const ushort4*)(divb + ((long)bi * TBB + q) * TBB + tid * 4);
  __syncthreads();

  const int gz = bi * 4 + wave;
  const unsigned short* srow = sim + ((long)gz * TBB + q) * TBB;
  float s[16], d[16];
#pragma unroll
  for (int u = 0; u < 4; ++u) {
    const ushort4 sv = *(const ushort4*)(srow + u * 256 + lane * 4);
    const ushort4 dv = *(const ushort4*)&sDiv[u * 256 + lane * 4];
    s[u * 4 + 0] = h2f(sv.x); s[u * 4 + 1] = h2f(sv.y);
    s[u * 4 + 2] = h2f(sv.z); s[u * 4 + 3] = h2f(sv.w);
    d[u * 4 + 0] = h2f(dv.x); d[u * 4 + 1] = h2f(dv.y);
    d[u * 4 + 2] = h2f(dv.z); d[u * 4 + 3] = h2f(dv.w);
  }
  float m = s[0];
#pragma unroll
  for (int i2 = 1; i2 < 16; ++i2) m = fmaxf(m, s[i2]);
  m = bMax(m);
  const float mB = m * 1.4426950408889634f;
  float l = 0.f, ss = 0.f, dn = 0.f, ds = 0.f;
#pragma unroll
  for (int i2 = 0; i2 < 16; ++i2) {
    const float e = exp2f(fmaf(s[i2], 1.4426950408889634f, -mB));
    l += e; ss += e * s[i2]; dn += e * d[i2]; ds += d[i2];
  }
  l = bSum(l); ss = bSum(ss); dn = bSum(dn); ds = bSum(ds);
  if (lane == 0) {
    const float Li = 1.f / l;
    const float lnL = logf(l);
    const long o2 = ((long)bi * 1024 + q) * 4 + wave;
    dep2[o2] = (dn * Li) / ds;
    ent2[o2] = (m + lnL - ss * Li) * 0.14426950408889634f;  // 1/ln(1024)
    Brow[(long)gz * TBB + q] = (m + lnL) * 1.4426950408889634f;
  }
}

extern "C" void kernel_launch(void* const* d_in, const int* in_sizes, int n_in,
                              void* d_out, int out_size, void* d_ws, size_t ws_size,
                              hipStream_t stream)
{
  const float* x  = (const float*)d_in[0];
  const float* Wq = (const float*)d_in[1];
  const float* Wk = (const float*)d_in[2];
  const float* Wv = (const float*)d_in[3];
  const float* Wo = (const float*)d_in[4];
  const float* W2 = (const float*)d_in[5];

  char* ws = (char*)d_ws;
  size_t off = 0;
  auto take = [&](size_t bytes) -> void* {
    void* p = ws + off;
    off += (bytes + 255) & ~(size_t)255;
    return p;
  };
  unsigned short* QKV = (unsigned short*)take((size_t)2 * TT * DD * 2);  // Q,K
  unsigned short* xh  = (unsigned short*)take((size_t)TT * DD * 2);
  unsigned short* xu  = (unsigned short*)take((size_t)TT * DD * 2);
  unsigned short* Wh  = (unsigned short*)take((size_t)3 * DD * DD * 2);
  unsigned short* WoB = (unsigned short*)take((size_t)DD * DD * 2);
  unsigned short* W2T = (unsigned short*)take((size_t)256 * 256 * 2);
  unsigned short* WFh = (unsigned short*)take((size_t)DD * DD * 2);
  float* Efold = (float*)take((size_t)4 * DD * 4);
  float* Dfold = (float*)take((size_t)4 * DD * 4);
  unsigned short* APh = (unsigned short*)take((size_t)TBB * TBB * 2);
  unsigned short* divb = (unsigned short*)take((size_t)4 * TBB * TBB * 2);
  unsigned short* Vt = (unsigned short*)take((size_t)DD * TT * 2);
  unsigned short* simh = (unsigned short*)take((size_t)16 * TBB * TBB * 2);
  float* dep2 = (float*)take((size_t)TT * 4 * 4);
  float* ent2 = (float*)take((size_t)TT * 4 * 4);
  float* Brow = (float*)take((size_t)16 * TBB * 4);
  unsigned short* ctxR = (unsigned short*)take((size_t)TT * DD * 2);
  (void)ws_size; (void)in_sizes; (void)n_in; (void)out_size;

  // 1) wide-parallel preprocessing
  prep_kernel<<<9536, 256, 0, stream>>>(x, Wq, Wk, Wv, Wo, W2,
                                        xh, xu, Wh, APh, WoB, W2T, Efold, Dfold);

  // 2) ALL prep-dependent GEMMs, all 128-tile, per-segment XCD chunking
  mega1_kernel<<<1088, 256, 0, stream>>>(
      xh, Wh, QKV, Vt, xu, divb, WoB, W2T, WFh);

  const unsigned short* Qh = QKV;
  const unsigned short* Kh = QKV + (size_t)TT * DD;

  // 3) sim = Qb @ Kb^T + APh (fp16 out), flat grid + XCD swizzle
  sim_gemm<<<1024, 256, 0, stream>>>(Qh, Kh, simh, APh);

  // 4) stats: flat grid, XCD-affine to div/sim producers
  stats_kernel<<<4096, 256, 0, stream>>>(simh, divb, dep2, ent2, Brow);

  // 5) ctxR + entnorm side-blocks, flat grid + XCD swizzle
  ctx_gemm_s<<<516, 256, 0, stream>>>(simh, dep2, Brow, Vt, ctxR, ent2);

  // 6) out = ctxR @ WFh^T + rank-8 epilogue, 128-tile, 1 block/CU, XCD-affine
  out_kernel<<<256, 256, 0, stream>>>(
      ctxR, WFh, (float*)d_out, ent2, dep2, Efold, Dfold);
}